// Round 6
// baseline (1139.318 us; speedup 1.0000x reference)
//
#include <hip/hip_runtime.h>
#include <hip/hip_bf16.h>

#define DM 512      // d_model
#define DI 1024     // d_inner
#define DSTATE 16
#define DTR 32      // dt_rank
#define NLAYER 8
#define BS 4
#define LL 256      // tokens per batch (F*NP)
#define MT 1024     // BS*LL total tokens
#define DPROJ 256
#define CL 32       // scan chunk length
#define NCH (LL/CL)

typedef unsigned short u16;
typedef __attribute__((ext_vector_type(8))) short short8;
typedef __attribute__((ext_vector_type(4))) float f32x4;

__device__ __forceinline__ float sigmoidf_(float x){ return 1.f/(1.f+__expf(-x)); }

// fp32 -> bf16 round-to-nearest-even (finite inputs)
__device__ __forceinline__ u16 f2bf(float f){
  unsigned u = __float_as_uint(f);
  u = (u + 0x7FFF + ((u>>16)&1)) >> 16;
  return (u16)u;
}

// VALU-pipe 16-lane sum via DPP row rotations
template<int CTRL>
__device__ __forceinline__ float dpp_ror_add(float x){
  int y = __builtin_amdgcn_update_dpp(0, __float_as_int(x), CTRL, 0xF, 0xF, false);
  return x + __int_as_float(y);
}
__device__ __forceinline__ float sum16_dpp(float x){
  x = dpp_ror_add<0x128>(x);
  x = dpp_ror_add<0x124>(x);
  x = dpp_ror_add<0x122>(x);
  x = dpp_ror_add<0x121>(x);
  return x;
}

// ---------------- patch embed
__global__ __launch_bounds__(256) void embed_k(const float* __restrict__ ts,
    const float* __restrict__ ew, const float* __restrict__ eb, float* __restrict__ x){
  int idx = blockIdx.x*256 + threadIdx.x;     // MT*DM
  int m = idx >> 9, d = idx & 511;
  int b = m >> 8, np_ = m & 255;
  const float* t0 = ts + b*1024 + np_*4;
  float acc = eb[d];
  #pragma unroll
  for (int p=0;p<4;p++) acc = fmaf(t0[p], ew[d*4+p], acc);
  x[idx] = acc;
}

// ---------------- cast ALL weights to bf16 once (concatenated dst)
__global__ __launch_bounds__(256) void wcastall_k(
    const float* __restrict__ w_in, const float* __restrict__ w_out,
    const float* __restrict__ w_xp, const float* __restrict__ w_dt,
    const float* __restrict__ w_pj, u16* __restrict__ dst){
  int t = blockIdx.x*256 + threadIdx.x;   // 6815744 float4s total
  const float* src; int o4;
  if      (t < 4194304) { src = w_in;  o4 = t; }
  else if (t < 6291456) { src = w_out; o4 = t - 4194304; }
  else if (t < 6553600) { src = w_xp;  o4 = t - 6291456; }
  else if (t < 6684672) { src = w_dt;  o4 = t - 6553600; }
  else                  { src = w_pj;  o4 = t - 6684672; }
  float4 v = ((const float4*)src)[o4];
  ushort4 r; r.x=f2bf(v.x); r.y=f2bf(v.y); r.z=f2bf(v.z); r.w=f2bf(v.w);
  ((ushort4*)dst)[t] = r;
}

// ---------------- fused (residual combine) + rmsnorm -> bf16 normal+flipped
__global__ __launch_bounds__(256) void rmscomb_k(float* __restrict__ x,
    const float* __restrict__ yout,   // nullptr for layer 0
    const float* __restrict__ nw, u16* __restrict__ xnbf, u16* __restrict__ xnfbf){
  int m = blockIdx.x, t = threadIdx.x;
  int b = m>>8, l = m&255, mf = (b<<8)+(255-l);
  float2 v = *(const float2*)&x[(long)m*DM + t*2];
  if (yout){
    float2 f = *(const float2*)&yout[(long)m*DM + t*2];
    float2 g = *(const float2*)&yout[(long)MT*DM + (long)mf*DM + t*2];
    v.x += f.x + g.x; v.y += f.y + g.y;
    *(float2*)&x[(long)m*DM + t*2] = v;
  }
  float ss = v.x*v.x + v.y*v.y;
  ss += __shfl_down(ss,32); ss += __shfl_down(ss,16); ss += __shfl_down(ss,8);
  ss += __shfl_down(ss,4);  ss += __shfl_down(ss,2);  ss += __shfl_down(ss,1);
  __shared__ float ps[4];
  if ((t&63)==0) ps[t>>6] = ss;
  __syncthreads();
  float tot = ps[0]+ps[1]+ps[2]+ps[3];
  float rs = rsqrtf(tot*(1.f/DM) + 1e-5f);
  ushort2 o; o.x = f2bf(v.x*rs*nw[t*2]); o.y = f2bf(v.y*rs*nw[t*2+1]);
  *(ushort2*)&xnbf [(long)m *DM + t*2] = o;
  *(ushort2*)&xnfbf[(long)mf*DM + t*2] = o;
}

// ---------------- final combine + cast to bf16 (x not written back)
__global__ __launch_bounds__(256) void combcast_k(const float* __restrict__ x,
    const float* __restrict__ yout, u16* __restrict__ xbf){
  int idx = blockIdx.x*256 + threadIdx.x;   // MT*DM/4
  int m = idx >> 7, c4 = idx & 127;
  int b = m>>8, l = m&255, mf = (b<<8)+(255-l);
  float4 r = ((const float4*)x)[idx];
  float4 f = ((const float4*)yout)[idx];
  float4 g = ((const float4*)(yout + (long)MT*DM))[(long)mf*128 + c4];
  ushort4 o;
  o.x = f2bf(r.x + f.x + g.x); o.y = f2bf(r.y + f.y + g.y);
  o.z = f2bf(r.z + f.z + g.z); o.w = f2bf(r.w + f.w + g.w);
  ((ushort4*)xbf)[idx] = o;
}

// ---------------- bf16 MFMA GEMM: C = A @ W^T
// A: (M,K) bf16 row-major; W: (N,K) bf16 row-major; C fp32.
// 256 threads = 4 waves (2x2). LDS [kgroup][row][8].
// EPI: 0 plain | 1 +bias(dir), softplus | 2 final scatter+bias | 3 plain + bf16 side-store of n<32
template<int BM,int BN,int EPI>
__global__ __launch_bounds__(256) void mfma_nt(
    const u16* __restrict__ A, int lda, long sA,
    const u16* __restrict__ W, int ldw, long sW,
    const float* __restrict__ bias, long sBias,
    u16* __restrict__ D2,
    float* __restrict__ C, int ldc, long sC,
    int M, int N, int K)
{
  constexpr int WM = BM/2, WN = BN/2;
  constexpr int MI = WM/16, NI = WN/16;
  int dir = blockIdx.z;
  A += (long)dir * sA;
  W += (long)dir * sW;
  C += (long)dir * sC;
  if (EPI==1) bias += (long)dir * sBias;

  __shared__ u16 Al[BM*32];
  __shared__ u16 Wl[BN*32];
  int tid = threadIdx.x;
  int lane = tid & 63;
  int wave = tid >> 6;
  int wm0 = (wave>>1)*WM, wn0 = (wave&1)*WN;
  int m0 = blockIdx.y*BM, n0 = blockIdx.x*BN;
  int l16 = lane>>4, l15 = lane&15;

  f32x4 acc[MI][NI] = {};

  for (int k0=0; k0<K; k0+=32){
    #pragma unroll
    for (int it=0; it<BM*4/256; ++it){
      int ch = it*256 + tid;
      int row = ch % BM, kk = ch / BM;
      const u16* g = A + (long)(m0+row)*lda + k0 + kk*8;
      __builtin_amdgcn_global_load_lds(
          (const __attribute__((address_space(1))) void*)g,
          (__attribute__((address_space(3))) void*)(Al + ch*8), 16, 0, 0);
    }
    #pragma unroll
    for (int it=0; it<BN*4/256; ++it){
      int ch = it*256 + tid;
      int row = ch % BN, kk = ch / BN;
      const u16* g = W + (long)(n0+row)*ldw + k0 + kk*8;
      __builtin_amdgcn_global_load_lds(
          (const __attribute__((address_space(1))) void*)g,
          (__attribute__((address_space(3))) void*)(Wl + ch*8), 16, 0, 0);
    }
    __syncthreads();
    short8 a[MI], b[NI];
    #pragma unroll
    for (int i=0;i<MI;i++)
      a[i] = *(const short8*)&Al[(l16*BM + wm0 + i*16 + l15)*8];
    #pragma unroll
    for (int j=0;j<NI;j++)
      b[j] = *(const short8*)&Wl[(l16*BN + wn0 + j*16 + l15)*8];
    #pragma unroll
    for (int i=0;i<MI;i++)
      #pragma unroll
      for (int j=0;j<NI;j++)
        acc[i][j] = __builtin_amdgcn_mfma_f32_16x16x32_bf16(a[i], b[j], acc[i][j], 0,0,0);
    __syncthreads();
  }
  #pragma unroll
  for (int i=0;i<MI;i++){
    #pragma unroll
    for (int j=0;j<NI;j++){
      #pragma unroll
      for (int r=0;r<4;r++){
        int m = m0 + wm0 + i*16 + l16*4 + r;
        int n = n0 + wn0 + j*16 + l15;
        float v = acc[i][j][r];
        if (EPI==1){
          v += bias[n];
          v = (v>20.f) ? v : log1pf(__expf(v));
          C[(long)m*ldc + n] = v;
        } else if (EPI==2){
          v += bias[n];
          int bb = m>>8, np_ = m&255, p = n>>8, dp = n&255;
          C[((long)(bb*1024 + np_*4 + p))*256 + dp] = v;
        } else if (EPI==3){
          C[(long)m*ldc + n] = v;
          if (n < 32) D2[((long)dir*M + m)*32 + n] = f2bf(v);
        } else {
          C[(long)m*ldc + n] = v;
        }
      }
    }
  }
}

// ---------------- causal depthwise conv + bias + silu; writes fp32 u and bf16 u
__global__ __launch_bounds__(256) void conv_silu_k(const float* __restrict__ xz,
    const float* __restrict__ cw, const float* __restrict__ cb,
    float* __restrict__ u, u16* __restrict__ ubf){
  long idx = (long)blockIdx.x*256 + threadIdx.x;  // 2*MT*DI
  int e  = (int)(idx & (DI-1));
  int dm = (int)(idx >> 10);
  int dir = dm >> 10;
  int m  = dm & (MT-1);
  int l  = m & (LL-1);
  const float* w = cw + ((long)dir*DI + e)*4;
  float acc = cb[dir*DI + e];
  const float* src = xz + (long)dm*2048 + e;
  #pragma unroll
  for (int j=0;j<4;j++){
    int ll = l - 3 + j;
    if (ll >= 0) acc = fmaf(w[j], src[(long)(j-3)*2048], acc);
  }
  float v = acc * sigmoidf_(acc);
  u[idx] = v;
  ubf[idx] = f2bf(v);
}

// ---------------- selective scan; epilogue writes gated y as bf16
__global__ __launch_bounds__(256) void scan_k(
    const float* __restrict__ delta, const float* __restrict__ u,
    const float* __restrict__ xz, const float* __restrict__ xdbl,
    const float* __restrict__ A_log, const float* __restrict__ Dp,
    u16* __restrict__ ygbf)
{
  int t = threadIdx.x;
  int n = t & 15, el = t >> 4;
  int ec = blockIdx.x, b = blockIdx.y, dir = blockIdx.z;
  int e0 = ec*16;
  int e = e0 + el;
  float Av = -__expf(A_log[((long)dir*DI + e)*16 + n]);
  float Dv = Dp[dir*DI + e];
  long mbase = (long)dir*MT + b*LL;
  const float* dp_ = delta + mbase*DI;
  const float* up_ = u     + mbase*DI;
  const float* zp_ = xz    + mbase*2048 + 1024;
  const float* bc_ = xdbl  + mbase*64 + 32;
  u16* yp_ = ygbf + mbase*DI;

  __shared__ float sDU[2][CL][32];
  __shared__ float sBC[2][CL][32];
  __shared__ float sy[CL][16];

  int lb  = t >> 3,        jb = (t & 7) * 4;
  int tt  = t & 127;
  int ld_ = tt >> 2,       ed = (tt & 3) * 4;

  float4 pbc, pdu;
  auto load_pre = [&](int c){
    long l0 = (long)c*CL;
    pbc = *(const float4*)&bc_[(l0+lb)*64 + jb];
    pdu = (t < 128) ? *(const float4*)&dp_[(l0+ld_)*DI + e0 + ed]
                    : *(const float4*)&up_[(l0+ld_)*DI + e0 + ed];
  };
  auto write_pre = [&](int buf){
    *(float4*)&sBC[buf][lb][jb] = pbc;
    if (t < 128) *(float4*)&sDU[buf][ld_][ed]      = pdu;
    else         *(float4*)&sDU[buf][ld_][16+ed]   = pdu;
  };

  load_pre(0);
  write_pre(0);
  load_pre(1);
  __syncthreads();

  float h = 0.f;
  for (int c = 0; c < NCH; ++c){
    int cur = c & 1;
    float4 zc;
    if (t < 128) zc = *(const float4*)&zp_[((long)c*CL + ld_)*2048 + e0 + ed];

    const float* du = &sDU[cur][0][el];
    const float* bc = &sBC[cur][0][n];
    #pragma unroll 8
    for (int l = 0; l < CL; ++l){
      float dv = du[l*32],     uv = du[l*32 + 16];
      float Bv = bc[l*32],     Cv = bc[l*32 + 16];
      float dA = __expf(dv*Av);
      h = fmaf(dA, h, dv*uv*Bv);
      float yc = sum16_dpp(h*Cv);
      if (n==0) sy[l][el] = yc + uv*Dv;
    }
    __syncthreads();
    if (c+1 < NCH){
      write_pre(cur^1);
      if (c+2 < NCH) load_pre(c+2);
    }
    if (t < 128){
      float4 y4 = *(const float4*)&sy[ld_][ed];
      float gx = zc.x*sigmoidf_(zc.x), gy = zc.y*sigmoidf_(zc.y);
      float gz = zc.z*sigmoidf_(zc.z), gw = zc.w*sigmoidf_(zc.w);
      ushort4 o; o.x=f2bf(y4.x*gx); o.y=f2bf(y4.y*gy); o.z=f2bf(y4.z*gz); o.w=f2bf(y4.w*gw);
      *(ushort4*)&yp_[((long)c*CL + ld_)*DI + e0 + ed] = o;
    }
    __syncthreads();
  }
}

extern "C" void kernel_launch(void* const* d_in, const int* in_sizes, int n_in,
                              void* d_out, int out_size, void* d_ws, size_t ws_size,
                              hipStream_t stream){
  const float* ts   = (const float*)d_in[0];
  const float* ew   = (const float*)d_in[2];
  const float* eb   = (const float*)d_in[3];
  const float* nw   = (const float*)d_in[4];
  const float* inw  = (const float*)d_in[5];
  const float* cw   = (const float*)d_in[6];
  const float* cb   = (const float*)d_in[7];
  const float* xpw  = (const float*)d_in[8];
  const float* dtw  = (const float*)d_in[9];
  const float* dtb  = (const float*)d_in[10];
  const float* alog = (const float*)d_in[11];
  const float* dpp  = (const float*)d_in[12];
  const float* outw = (const float*)d_in[13];
  const float* pw   = (const float*)d_in[14];
  const float* pb   = (const float*)d_in[15];
  float* out = (float*)d_out;

  float* ws   = (float*)d_ws;
  float* x    = ws;                  // 524288
  float* xz   = ws + 524288;         // 4194304
  float* u    = ws + 4718592;        // 2097152
  float* xdbl = ws + 6815744;        // 131072
  float* delta= ws + 6946816;        // 2097152
  float* yout = ws + 9043968;        // 1048576
  u16* ub     = (u16*)(ws + 10092544);
  u16* xn_bf  = ub;                  // 1048576 (both dirs)
  u16* u_bf   = ub + 1048576;        // 2097152
  u16* yg_bf  = ub + 3145728;        // 2097152
  u16* x_bf   = ub + 5242880;        // 524288
  u16* dt_bf  = ub + 5767168;        // 65536
  u16* wb     = ub + 5832704;        // 27262976 total bf16 weights
  u16* wb_in  = wb;                  // 16777216
  u16* wb_out = wb + 16777216;       // 8388608
  u16* wb_xp  = wb + 25165824;       // 1048576
  u16* wb_dt  = wb + 26214400;       // 524288
  u16* wb_pj  = wb + 26738688;       // 524288

  dim3 blk(256);

  embed_k<<<MT*DM/256, blk, 0, stream>>>(ts, ew, eb, x);
  wcastall_k<<<26624, blk, 0, stream>>>(inw, outw, xpw, dtw, pw, wb);

  for (int i=0;i<NLAYER;i++){
    rmscomb_k<<<MT, blk, 0, stream>>>(x, i ? yout : nullptr, nw + i*DM,
        xn_bf, xn_bf + MT*DM);
    // in_proj: (1024x512)@(2048x512)^T -> xz fp32, per dir
    mfma_nt<128,128,0><<<dim3(16,8,2), blk, 0, stream>>>(
        xn_bf, DM, (long)MT*DM, wb_in + (long)i*2097152, DM, 1048576,
        nullptr, 0, nullptr, xz, 2048, (long)MT*2048, MT, 2048, DM);
    conv_silu_k<<<2*MT*DI/256, blk, 0, stream>>>(xz, cw + (long)i*2*DI*4, cb + i*2*DI, u, u_bf);
    // xproj: (1024x1024)@(64x1024)^T -> xdbl fp32 + bf16 dt side-store
    mfma_nt<128,64,3><<<dim3(1,8,2), blk, 0, stream>>>(
        u_bf, DI, (long)MT*DI, wb_xp + (long)i*131072, DI, 65536,
        nullptr, 0, dt_bf, xdbl, 64, (long)MT*64, MT, 64, DI);
    // delta = softplus(dt @ dt_w^T + dt_b)  (bf16 MFMA, K=32)
    mfma_nt<128,64,1><<<dim3(16,8,2), blk, 0, stream>>>(
        dt_bf, DTR, (long)MT*DTR, wb_dt + (long)i*65536, DTR, 32768,
        dtb + (long)i*2*DI, DI, nullptr, delta, DI, (long)MT*DI, MT, DI, DTR);
    scan_k<<<dim3(64, BS, 2), blk, 0, stream>>>(delta, u, xz, xdbl,
        alog + (long)i*2*DI*16, dpp + i*2*DI, yg_bf);
    // out_proj: (1024x1024)@(512x1024)^T -> yout fp32
    mfma_nt<128,64,0><<<dim3(8,8,2), blk, 0, stream>>>(
        yg_bf, DI, (long)MT*DI, wb_out + (long)i*1048576, DI, 524288,
        nullptr, 0, nullptr, yout, DM, (long)MT*DM, MT, DM, DI);
  }
  combcast_k<<<MT*DM/4/256, blk, 0, stream>>>(x, yout, x_bf);
  // final proj + bias + scatter
  mfma_nt<128,64,2><<<dim3(16,8,1), blk, 0, stream>>>(
      x_bf, DM, 0, wb_pj, DM, 0, pb, 0, nullptr, out, 1024, 0, MT, 1024, DM);
}

// Round 7
// 994.706 us; speedup vs baseline: 1.1454x; 1.1454x over previous
//
#include <hip/hip_runtime.h>
#include <hip/hip_bf16.h>

#define DM 512      // d_model
#define DI 1024     // d_inner
#define DSTATE 16
#define DTR 32      // dt_rank
#define NLAYER 8
#define BS 4
#define LL 256      // tokens per batch (F*NP)
#define MT 1024     // BS*LL total tokens
#define DPROJ 256
#define CL 32       // scan chunk length
#define NCH (LL/CL)

typedef unsigned short u16;
typedef __attribute__((ext_vector_type(8))) short short8;
typedef __attribute__((ext_vector_type(8))) unsigned short ushort8v;
typedef __attribute__((ext_vector_type(4))) float f32x4;

__device__ __forceinline__ float sigmoidf_(float x){ return 1.f/(1.f+__expf(-x)); }

// fp32 -> bf16 round-to-nearest-even (finite inputs)
__device__ __forceinline__ u16 f2bf(float f){
  unsigned u = __float_as_uint(f);
  u = (u + 0x7FFF + ((u>>16)&1)) >> 16;
  return (u16)u;
}

// VALU-pipe 16-lane sum via DPP row rotations
template<int CTRL>
__device__ __forceinline__ float dpp_ror_add(float x){
  int y = __builtin_amdgcn_update_dpp(0, __float_as_int(x), CTRL, 0xF, 0xF, false);
  return x + __int_as_float(y);
}
__device__ __forceinline__ float sum16_dpp(float x){
  x = dpp_ror_add<0x128>(x);
  x = dpp_ror_add<0x124>(x);
  x = dpp_ror_add<0x122>(x);
  x = dpp_ror_add<0x121>(x);
  return x;
}

// ---------------- patch embed
__global__ __launch_bounds__(256) void embed_k(const float* __restrict__ ts,
    const float* __restrict__ ew, const float* __restrict__ eb, float* __restrict__ x){
  int idx = blockIdx.x*256 + threadIdx.x;     // MT*DM
  int m = idx >> 9, d = idx & 511;
  int b = m >> 8, np_ = m & 255;
  const float* t0 = ts + b*1024 + np_*4;
  float acc = eb[d];
  #pragma unroll
  for (int p=0;p<4;p++) acc = fmaf(t0[p], ew[d*4+p], acc);
  x[idx] = acc;
}

// ---------------- cast ALL weights to bf16 once; 8 elems/thread, 16B stores
__global__ __launch_bounds__(256) void wcastall_k(
    const float* __restrict__ w_in, const float* __restrict__ w_out,
    const float* __restrict__ w_xp, const float* __restrict__ w_dt,
    const float* __restrict__ w_pj, u16* __restrict__ dst){
  long t = (long)blockIdx.x*256 + threadIdx.x;   // 3407872 threads
  long e8 = t*8;
  const float* src; long o;
  if      (e8 < 16777216) { src = w_in;  o = e8; }
  else if (e8 < 25165824) { src = w_out; o = e8 - 16777216; }
  else if (e8 < 26214400) { src = w_xp;  o = e8 - 25165824; }
  else if (e8 < 26738688) { src = w_dt;  o = e8 - 26214400; }
  else                    { src = w_pj;  o = e8 - 26738688; }
  float4 a = *(const float4*)(src + o);
  float4 b = *(const float4*)(src + o + 4);
  ushort8v r;
  r[0]=f2bf(a.x); r[1]=f2bf(a.y); r[2]=f2bf(a.z); r[3]=f2bf(a.w);
  r[4]=f2bf(b.x); r[5]=f2bf(b.y); r[6]=f2bf(b.z); r[7]=f2bf(b.w);
  *(ushort8v*)(dst + e8) = r;
}

// ---------------- fused (residual combine) + rmsnorm -> bf16 normal+flipped
__global__ __launch_bounds__(256) void rmscomb_k(float* __restrict__ x,
    const float* __restrict__ yout,   // nullptr for layer 0
    const float* __restrict__ nw, u16* __restrict__ xnbf, u16* __restrict__ xnfbf){
  int m = blockIdx.x, t = threadIdx.x;
  int b = m>>8, l = m&255, mf = (b<<8)+(255-l);
  float2 v = *(const float2*)&x[(long)m*DM + t*2];
  if (yout){
    float2 f = *(const float2*)&yout[(long)m*DM + t*2];
    float2 g = *(const float2*)&yout[(long)MT*DM + (long)mf*DM + t*2];
    v.x += f.x + g.x; v.y += f.y + g.y;
    *(float2*)&x[(long)m*DM + t*2] = v;
  }
  float ss = v.x*v.x + v.y*v.y;
  ss += __shfl_down(ss,32); ss += __shfl_down(ss,16); ss += __shfl_down(ss,8);
  ss += __shfl_down(ss,4);  ss += __shfl_down(ss,2);  ss += __shfl_down(ss,1);
  __shared__ float ps[4];
  if ((t&63)==0) ps[t>>6] = ss;
  __syncthreads();
  float tot = ps[0]+ps[1]+ps[2]+ps[3];
  float rs = rsqrtf(tot*(1.f/DM) + 1e-5f);
  ushort2 o; o.x = f2bf(v.x*rs*nw[t*2]); o.y = f2bf(v.y*rs*nw[t*2+1]);
  *(ushort2*)&xnbf [(long)m *DM + t*2] = o;
  *(ushort2*)&xnfbf[(long)mf*DM + t*2] = o;
}

// ---------------- final combine + cast to bf16
__global__ __launch_bounds__(256) void combcast_k(const float* __restrict__ x,
    const float* __restrict__ yout, u16* __restrict__ xbf){
  int idx = blockIdx.x*256 + threadIdx.x;   // MT*DM/4
  int m = idx >> 7, c4 = idx & 127;
  int b = m>>8, l = m&255, mf = (b<<8)+(255-l);
  float4 r = ((const float4*)x)[idx];
  float4 f = ((const float4*)yout)[idx];
  float4 g = ((const float4*)(yout + (long)MT*DM))[(long)mf*128 + c4];
  ushort4 o;
  o.x = f2bf(r.x + f.x + g.x); o.y = f2bf(r.y + f.y + g.y);
  o.z = f2bf(r.z + f.z + g.z); o.w = f2bf(r.w + f.w + g.w);
  ((ushort4*)xbf)[idx] = o;
}

// ---------------- bf16 MFMA GEMM: C = A @ W^T
// A: (M,K) bf16 row-major; W: (N,K) bf16 row-major; C fp32.
// SPLITK>1: z = dir*SPLITK+kc, fp32 partials at C + z*M*N.
// EPI: 0 plain | 1 +bias(dir), softplus | 2 final scatter+bias
template<int BM,int BN,int SPLITK,int EPI>
__global__ __launch_bounds__(256) void mfma_nt(
    const u16* __restrict__ A, int lda, long sA,
    const u16* __restrict__ W, int ldw, long sW,
    const float* __restrict__ bias, long sBias,
    float* __restrict__ C, int ldc, long sC,
    int M, int N, int K)
{
  constexpr int WM = BM/2, WN = BN/2;
  constexpr int MI = WM/16, NI = WN/16;
  int z = blockIdx.z;
  int dir = z / SPLITK, kc = z % SPLITK;
  int Klen = K / SPLITK;
  int kbase = kc * Klen;
  A += (long)dir * sA;
  W += (long)dir * sW;
  if (SPLITK > 1) C += (long)z * M * N; else C += (long)dir * sC;
  if (EPI==1) bias += (long)dir * sBias;

  __shared__ u16 Al[BM*32];
  __shared__ u16 Wl[BN*32];
  int tid = threadIdx.x;
  int lane = tid & 63;
  int wave = tid >> 6;
  int wm0 = (wave>>1)*WM, wn0 = (wave&1)*WN;
  int m0 = blockIdx.y*BM, n0 = blockIdx.x*BN;
  int l16 = lane>>4, l15 = lane&15;

  f32x4 acc[MI][NI] = {};

  for (int k0=0; k0<Klen; k0+=32){
    #pragma unroll
    for (int it=0; it<BM*4/256; ++it){
      int ch = it*256 + tid;
      int row = ch % BM, kk = ch / BM;
      const u16* g = A + (long)(m0+row)*lda + kbase + k0 + kk*8;
      __builtin_amdgcn_global_load_lds(
          (const __attribute__((address_space(1))) void*)g,
          (__attribute__((address_space(3))) void*)(Al + ch*8), 16, 0, 0);
    }
    #pragma unroll
    for (int it=0; it<BN*4/256; ++it){
      int ch = it*256 + tid;
      int row = ch % BN, kk = ch / BN;
      const u16* g = W + (long)(n0+row)*ldw + kbase + k0 + kk*8;
      __builtin_amdgcn_global_load_lds(
          (const __attribute__((address_space(1))) void*)g,
          (__attribute__((address_space(3))) void*)(Wl + ch*8), 16, 0, 0);
    }
    __syncthreads();
    short8 a[MI], b[NI];
    #pragma unroll
    for (int i=0;i<MI;i++)
      a[i] = *(const short8*)&Al[(l16*BM + wm0 + i*16 + l15)*8];
    #pragma unroll
    for (int j=0;j<NI;j++)
      b[j] = *(const short8*)&Wl[(l16*BN + wn0 + j*16 + l15)*8];
    #pragma unroll
    for (int i=0;i<MI;i++)
      #pragma unroll
      for (int j=0;j<NI;j++)
        acc[i][j] = __builtin_amdgcn_mfma_f32_16x16x32_bf16(a[i], b[j], acc[i][j], 0,0,0);
    __syncthreads();
  }
  #pragma unroll
  for (int i=0;i<MI;i++){
    #pragma unroll
    for (int j=0;j<NI;j++){
      #pragma unroll
      for (int r=0;r<4;r++){
        int m = m0 + wm0 + i*16 + l16*4 + r;
        int n = n0 + wn0 + j*16 + l15;
        float v = acc[i][j][r];
        if (EPI==1){
          v += bias[n];
          v = (v>20.f) ? v : log1pf(__expf(v));
          C[(long)m*ldc + n] = v;
        } else if (EPI==2){
          v += bias[n];
          int bb = m>>8, np_ = m&255, p = n>>8, dp = n&255;
          C[((long)(bb*1024 + np_*4 + p))*256 + dp] = v;
        } else {
          C[(long)m*ldc + n] = v;
        }
      }
    }
  }
}

// ---------------- split-K reduce for xproj + bf16 dt side-product
__global__ __launch_bounds__(256) void xreduce_k(const float* __restrict__ part,
    float* __restrict__ xdbl, u16* __restrict__ dtbf){
  int idx = blockIdx.x*256 + threadIdx.x;   // 131072
  int d = idx >> 16, off = idx & 65535;
  float s = 0.f;
  #pragma unroll
  for (int kc=0; kc<8; ++kc) s += part[((d*8+kc)<<16) + off];
  xdbl[idx] = s;
  int col = off & 63;
  if (col < 32){
    int m = off >> 6;
    dtbf[((long)d*MT + m)*32 + col] = f2bf(s);
  }
}

// ---------------- causal depthwise conv + bias + silu; writes fp32 u and bf16 u
__global__ __launch_bounds__(256) void conv_silu_k(const float* __restrict__ xz,
    const float* __restrict__ cw, const float* __restrict__ cb,
    float* __restrict__ u, u16* __restrict__ ubf){
  long idx = (long)blockIdx.x*256 + threadIdx.x;  // 2*MT*DI
  int e  = (int)(idx & (DI-1));
  int dm = (int)(idx >> 10);
  int dir = dm >> 10;
  int m  = dm & (MT-1);
  int l  = m & (LL-1);
  const float* w = cw + ((long)dir*DI + e)*4;
  float acc = cb[dir*DI + e];
  const float* src = xz + (long)dm*2048 + e;
  #pragma unroll
  for (int j=0;j<4;j++){
    int ll = l - 3 + j;
    if (ll >= 0) acc = fmaf(w[j], src[(long)(j-3)*2048], acc);
  }
  float v = acc * sigmoidf_(acc);
  u[idx] = v;
  ubf[idx] = f2bf(v);
}

// ---------------- selective scan; epilogue writes gated y as bf16
__global__ __launch_bounds__(256) void scan_k(
    const float* __restrict__ delta, const float* __restrict__ u,
    const float* __restrict__ xz, const float* __restrict__ xdbl,
    const float* __restrict__ A_log, const float* __restrict__ Dp,
    u16* __restrict__ ygbf)
{
  int t = threadIdx.x;
  int n = t & 15, el = t >> 4;
  int ec = blockIdx.x, b = blockIdx.y, dir = blockIdx.z;
  int e0 = ec*16;
  int e = e0 + el;
  float Av = -__expf(A_log[((long)dir*DI + e)*16 + n]);
  float Dv = Dp[dir*DI + e];
  long mbase = (long)dir*MT + b*LL;
  const float* dp_ = delta + mbase*DI;
  const float* up_ = u     + mbase*DI;
  const float* zp_ = xz    + mbase*2048 + 1024;
  const float* bc_ = xdbl  + mbase*64 + 32;
  u16* yp_ = ygbf + mbase*DI;

  __shared__ float sDU[2][CL][32];
  __shared__ float sBC[2][CL][32];
  __shared__ float sy[CL][16];

  int lb  = t >> 3,        jb = (t & 7) * 4;
  int tt  = t & 127;
  int ld_ = tt >> 2,       ed = (tt & 3) * 4;

  float4 pbc, pdu;
  auto load_pre = [&](int c){
    long l0 = (long)c*CL;
    pbc = *(const float4*)&bc_[(l0+lb)*64 + jb];
    pdu = (t < 128) ? *(const float4*)&dp_[(l0+ld_)*DI + e0 + ed]
                    : *(const float4*)&up_[(l0+ld_)*DI + e0 + ed];
  };
  auto write_pre = [&](int buf){
    *(float4*)&sBC[buf][lb][jb] = pbc;
    if (t < 128) *(float4*)&sDU[buf][ld_][ed]      = pdu;
    else         *(float4*)&sDU[buf][ld_][16+ed]   = pdu;
  };

  load_pre(0);
  write_pre(0);
  load_pre(1);
  __syncthreads();

  float h = 0.f;
  for (int c = 0; c < NCH; ++c){
    int cur = c & 1;
    float4 zc;
    if (t < 128) zc = *(const float4*)&zp_[((long)c*CL + ld_)*2048 + e0 + ed];

    const float* du = &sDU[cur][0][el];
    const float* bc = &sBC[cur][0][n];
    #pragma unroll 8
    for (int l = 0; l < CL; ++l){
      float dv = du[l*32],     uv = du[l*32 + 16];
      float Bv = bc[l*32],     Cv = bc[l*32 + 16];
      float dA = __expf(dv*Av);
      h = fmaf(dA, h, dv*uv*Bv);
      float yc = sum16_dpp(h*Cv);
      if (n==0) sy[l][el] = yc + uv*Dv;
    }
    __syncthreads();
    if (c+1 < NCH){
      write_pre(cur^1);
      if (c+2 < NCH) load_pre(c+2);
    }
    if (t < 128){
      float4 y4 = *(const float4*)&sy[ld_][ed];
      float gx = zc.x*sigmoidf_(zc.x), gy = zc.y*sigmoidf_(zc.y);
      float gz = zc.z*sigmoidf_(zc.z), gw = zc.w*sigmoidf_(zc.w);
      ushort4 o; o.x=f2bf(y4.x*gx); o.y=f2bf(y4.y*gy); o.z=f2bf(y4.z*gz); o.w=f2bf(y4.w*gw);
      *(ushort4*)&yp_[((long)c*CL + ld_)*DI + e0 + ed] = o;
    }
    __syncthreads();
  }
}

extern "C" void kernel_launch(void* const* d_in, const int* in_sizes, int n_in,
                              void* d_out, int out_size, void* d_ws, size_t ws_size,
                              hipStream_t stream){
  const float* ts   = (const float*)d_in[0];
  const float* ew   = (const float*)d_in[2];
  const float* eb   = (const float*)d_in[3];
  const float* nw   = (const float*)d_in[4];
  const float* inw  = (const float*)d_in[5];
  const float* cw   = (const float*)d_in[6];
  const float* cb   = (const float*)d_in[7];
  const float* xpw  = (const float*)d_in[8];
  const float* dtw  = (const float*)d_in[9];
  const float* dtb  = (const float*)d_in[10];
  const float* alog = (const float*)d_in[11];
  const float* dpp  = (const float*)d_in[12];
  const float* outw = (const float*)d_in[13];
  const float* pw   = (const float*)d_in[14];
  const float* pb   = (const float*)d_in[15];
  float* out = (float*)d_out;

  float* ws   = (float*)d_ws;
  float* x    = ws;                  // 524288
  float* xz   = ws + 524288;         // 4194304
  float* u    = ws + 4718592;        // 2097152
  float* xdbl = ws + 6815744;        // 131072
  float* delta= ws + 6946816;        // 2097152
  float* yout = ws + 9043968;        // 1048576
  float* xpart= ws + 10092544;       // 1048576 (2*8*65536)
  u16* ub     = (u16*)(ws + 11141120);
  u16* xn_bf  = ub;                  // 1048576 (both dirs)
  u16* u_bf   = ub + 1048576;        // 2097152
  u16* yg_bf  = ub + 3145728;        // 2097152
  u16* x_bf   = ub + 5242880;        // 524288
  u16* dt_bf  = ub + 5767168;        // 65536
  u16* wb     = ub + 5832704;        // 27262976 total bf16 weights
  u16* wb_in  = wb;                  // 16777216
  u16* wb_out = wb + 16777216;       // 8388608
  u16* wb_xp  = wb + 25165824;       // 1048576
  u16* wb_dt  = wb + 26214400;       // 524288
  u16* wb_pj  = wb + 26738688;       // 524288

  dim3 blk(256);

  embed_k<<<MT*DM/256, blk, 0, stream>>>(ts, ew, eb, x);
  wcastall_k<<<13312, blk, 0, stream>>>(inw, outw, xpw, dtw, pw, wb);

  for (int i=0;i<NLAYER;i++){
    rmscomb_k<<<MT, blk, 0, stream>>>(x, i ? yout : nullptr, nw + i*DM,
        xn_bf, xn_bf + MT*DM);
    // in_proj: (1024x512)@(2048x512)^T -> xz fp32, per dir
    mfma_nt<128,128,1,0><<<dim3(16,8,2), blk, 0, stream>>>(
        xn_bf, DM, (long)MT*DM, wb_in + (long)i*2097152, DM, 1048576,
        nullptr, 0, xz, 2048, (long)MT*2048, MT, 2048, DM);
    conv_silu_k<<<2*MT*DI/256, blk, 0, stream>>>(xz, cw + (long)i*2*DI*4, cb + i*2*DI, u, u_bf);
    // xproj: (1024x1024)@(64x1024)^T split-K=8 -> partials
    mfma_nt<128,64,8,0><<<dim3(1,8,16), blk, 0, stream>>>(
        u_bf, DI, (long)MT*DI, wb_xp + (long)i*131072, DI, 65536,
        nullptr, 0, xpart, 64, 0, MT, 64, DI);
    xreduce_k<<<512, blk, 0, stream>>>(xpart, xdbl, dt_bf);
    // delta = softplus(dt @ dt_w^T + dt_b)  (bf16 MFMA, K=32)
    mfma_nt<128,64,1,1><<<dim3(16,8,2), blk, 0, stream>>>(
        dt_bf, DTR, (long)MT*DTR, wb_dt + (long)i*65536, DTR, 32768,
        dtb + (long)i*2*DI, DI, delta, DI, (long)MT*DI, MT, DI, DTR);
    scan_k<<<dim3(64, BS, 2), blk, 0, stream>>>(delta, u, xz, xdbl,
        alog + (long)i*2*DI*16, dpp + i*2*DI, yg_bf);
    // out_proj: (1024x1024)@(512x1024)^T -> yout fp32
    mfma_nt<128,64,1,0><<<dim3(8,8,2), blk, 0, stream>>>(
        yg_bf, DI, (long)MT*DI, wb_out + (long)i*1048576, DI, 524288,
        nullptr, 0, yout, DM, (long)MT*DM, MT, DM, DI);
  }
  combcast_k<<<MT*DM/4/256, blk, 0, stream>>>(x, yout, x_bf);
  // final proj + bias + scatter
  mfma_nt<128,64,1,2><<<dim3(16,8,1), blk, 0, stream>>>(
      x_bf, DM, 0, wb_pj, DM, 0, pb, 0, out, 1024, 0, MT, 1024, DM);
}

// Round 8
// 839.617 us; speedup vs baseline: 1.3569x; 1.1847x over previous
//
#include <hip/hip_runtime.h>
#include <hip/hip_bf16.h>

#define DM 512      // d_model
#define DI 1024     // d_inner
#define DSTATE 16
#define DTR 32      // dt_rank
#define NLAYER 8
#define BS 4
#define LL 256      // tokens per batch (F*NP)
#define MT 1024     // BS*LL total tokens
#define DPROJ 256
#define CL 32       // scan chunk length
#define NCH (LL/CL)

typedef unsigned short u16;
typedef __attribute__((ext_vector_type(8))) short short8;
typedef __attribute__((ext_vector_type(8))) unsigned short ushort8v;
typedef __attribute__((ext_vector_type(4))) float f32x4;

__device__ __forceinline__ float sigmoidf_(float x){ return 1.f/(1.f+__expf(-x)); }

// fp32 -> bf16 round-to-nearest-even (finite inputs)
__device__ __forceinline__ u16 f2bf(float f){
  unsigned u = __float_as_uint(f);
  u = (u + 0x7FFF + ((u>>16)&1)) >> 16;
  return (u16)u;
}

// VALU-pipe 16-lane sum via DPP row rotations
template<int CTRL>
__device__ __forceinline__ float dpp_ror_add(float x){
  int y = __builtin_amdgcn_update_dpp(0, __float_as_int(x), CTRL, 0xF, 0xF, false);
  return x + __int_as_float(y);
}
__device__ __forceinline__ float sum16_dpp(float x){
  x = dpp_ror_add<0x128>(x);
  x = dpp_ror_add<0x124>(x);
  x = dpp_ror_add<0x122>(x);
  x = dpp_ror_add<0x121>(x);
  return x;
}

// ---------------- patch embed
__global__ __launch_bounds__(256) void embed_k(const float* __restrict__ ts,
    const float* __restrict__ ew, const float* __restrict__ eb, float* __restrict__ x){
  int idx = blockIdx.x*256 + threadIdx.x;     // MT*DM
  int m = idx >> 9, d = idx & 511;
  int b = m >> 8, np_ = m & 255;
  const float* t0 = ts + b*1024 + np_*4;
  float acc = eb[d];
  #pragma unroll
  for (int p=0;p<4;p++) acc = fmaf(t0[p], ew[d*4+p], acc);
  x[idx] = acc;
}

// ---------------- cast ALL weights to bf16 once; 16 elems/thread
__global__ __launch_bounds__(256) void wcastall_k(
    const float* __restrict__ w_in, const float* __restrict__ w_out,
    const float* __restrict__ w_xp, const float* __restrict__ w_dt,
    const float* __restrict__ w_pj, u16* __restrict__ dst){
  long t = (long)blockIdx.x*256 + threadIdx.x;   // 1703936 threads
  long e16 = t*16;
  const float* src; long o;
  if      (e16 < 16777216) { src = w_in;  o = e16; }
  else if (e16 < 25165824) { src = w_out; o = e16 - 16777216; }
  else if (e16 < 26214400) { src = w_xp;  o = e16 - 25165824; }
  else if (e16 < 26738688) { src = w_dt;  o = e16 - 26214400; }
  else                     { src = w_pj;  o = e16 - 26738688; }
  float4 a = *(const float4*)(src + o);
  float4 b = *(const float4*)(src + o + 4);
  float4 c = *(const float4*)(src + o + 8);
  float4 d = *(const float4*)(src + o + 12);
  ushort8v r0, r1;
  r0[0]=f2bf(a.x); r0[1]=f2bf(a.y); r0[2]=f2bf(a.z); r0[3]=f2bf(a.w);
  r0[4]=f2bf(b.x); r0[5]=f2bf(b.y); r0[6]=f2bf(b.z); r0[7]=f2bf(b.w);
  r1[0]=f2bf(c.x); r1[1]=f2bf(c.y); r1[2]=f2bf(c.z); r1[3]=f2bf(c.w);
  r1[4]=f2bf(d.x); r1[5]=f2bf(d.y); r1[6]=f2bf(d.z); r1[7]=f2bf(d.w);
  *(ushort8v*)(dst + e16) = r0;
  *(ushort8v*)(dst + e16 + 8) = r1;
}

// ---------------- fused (residual combine) + rmsnorm -> bf16 normal+flipped
__global__ __launch_bounds__(256) void rmscomb_k(float* __restrict__ x,
    const float* __restrict__ yout,   // nullptr for layer 0
    const float* __restrict__ nw, u16* __restrict__ xnbf, u16* __restrict__ xnfbf){
  int m = blockIdx.x, t = threadIdx.x;
  int b = m>>8, l = m&255, mf = (b<<8)+(255-l);
  float2 v = *(const float2*)&x[(long)m*DM + t*2];
  if (yout){
    float2 f = *(const float2*)&yout[(long)m*DM + t*2];
    float2 g = *(const float2*)&yout[(long)MT*DM + (long)mf*DM + t*2];
    v.x += f.x + g.x; v.y += f.y + g.y;
    *(float2*)&x[(long)m*DM + t*2] = v;
  }
  float ss = v.x*v.x + v.y*v.y;
  ss += __shfl_down(ss,32); ss += __shfl_down(ss,16); ss += __shfl_down(ss,8);
  ss += __shfl_down(ss,4);  ss += __shfl_down(ss,2);  ss += __shfl_down(ss,1);
  __shared__ float ps[4];
  if ((t&63)==0) ps[t>>6] = ss;
  __syncthreads();
  float tot = ps[0]+ps[1]+ps[2]+ps[3];
  float rs = rsqrtf(tot*(1.f/DM) + 1e-5f);
  ushort2 o; o.x = f2bf(v.x*rs*nw[t*2]); o.y = f2bf(v.y*rs*nw[t*2+1]);
  *(ushort2*)&xnbf [(long)m *DM + t*2] = o;
  *(ushort2*)&xnfbf[(long)mf*DM + t*2] = o;
}

// ---------------- final combine + cast to bf16
__global__ __launch_bounds__(256) void combcast_k(const float* __restrict__ x,
    const float* __restrict__ yout, u16* __restrict__ xbf){
  int idx = blockIdx.x*256 + threadIdx.x;   // MT*DM/4
  int m = idx >> 7, c4 = idx & 127;
  int b = m>>8, l = m&255, mf = (b<<8)+(255-l);
  float4 r = ((const float4*)x)[idx];
  float4 f = ((const float4*)yout)[idx];
  float4 g = ((const float4*)(yout + (long)MT*DM))[(long)mf*128 + c4];
  ushort4 o;
  o.x = f2bf(r.x + f.x + g.x); o.y = f2bf(r.y + f.y + g.y);
  o.z = f2bf(r.z + f.z + g.z); o.w = f2bf(r.w + f.w + g.w);
  ((ushort4*)xbf)[idx] = o;
}

// ---------------- bf16 MFMA GEMM: C = A @ W^T
// A: (M,K) bf16 row-major; W: (N,K) bf16 row-major; C fp32.
// SPLITK>1: z = dir*SPLITK+kc, fp32 partials at C + z*M*N.
// EPI: 0 plain | 1 +bias(dir), softplus | 2 final scatter+bias
template<int BM,int BN,int SPLITK,int EPI>
__global__ __launch_bounds__(256) void mfma_nt(
    const u16* __restrict__ A, int lda, long sA,
    const u16* __restrict__ W, int ldw, long sW,
    const float* __restrict__ bias, long sBias,
    float* __restrict__ C, int ldc, long sC,
    int M, int N, int K)
{
  constexpr int WM = BM/2, WN = BN/2;
  constexpr int MI = WM/16, NI = WN/16;
  int z = blockIdx.z;
  int dir = z / SPLITK, kc = z % SPLITK;
  int Klen = K / SPLITK;
  int kbase = kc * Klen;
  A += (long)dir * sA;
  W += (long)dir * sW;
  if (SPLITK > 1) C += (long)z * M * N; else C += (long)dir * sC;
  if (EPI==1) bias += (long)dir * sBias;

  __shared__ u16 Al[BM*32];
  __shared__ u16 Wl[BN*32];
  int tid = threadIdx.x;
  int lane = tid & 63;
  int wave = tid >> 6;
  int wm0 = (wave>>1)*WM, wn0 = (wave&1)*WN;
  int m0 = blockIdx.y*BM, n0 = blockIdx.x*BN;
  int l16 = lane>>4, l15 = lane&15;

  f32x4 acc[MI][NI] = {};

  for (int k0=0; k0<Klen; k0+=32){
    #pragma unroll
    for (int it=0; it<BM*4/256; ++it){
      int ch = it*256 + tid;
      int row = ch % BM, kk = ch / BM;
      const u16* g = A + (long)(m0+row)*lda + kbase + k0 + kk*8;
      __builtin_amdgcn_global_load_lds(
          (const __attribute__((address_space(1))) void*)g,
          (__attribute__((address_space(3))) void*)(Al + ch*8), 16, 0, 0);
    }
    #pragma unroll
    for (int it=0; it<BN*4/256; ++it){
      int ch = it*256 + tid;
      int row = ch % BN, kk = ch / BN;
      const u16* g = W + (long)(n0+row)*ldw + kbase + k0 + kk*8;
      __builtin_amdgcn_global_load_lds(
          (const __attribute__((address_space(1))) void*)g,
          (__attribute__((address_space(3))) void*)(Wl + ch*8), 16, 0, 0);
    }
    __syncthreads();
    short8 a[MI], b[NI];
    #pragma unroll
    for (int i=0;i<MI;i++)
      a[i] = *(const short8*)&Al[(l16*BM + wm0 + i*16 + l15)*8];
    #pragma unroll
    for (int j=0;j<NI;j++)
      b[j] = *(const short8*)&Wl[(l16*BN + wn0 + j*16 + l15)*8];
    #pragma unroll
    for (int i=0;i<MI;i++)
      #pragma unroll
      for (int j=0;j<NI;j++)
        acc[i][j] = __builtin_amdgcn_mfma_f32_16x16x32_bf16(a[i], b[j], acc[i][j], 0,0,0);
    __syncthreads();
  }
  #pragma unroll
  for (int i=0;i<MI;i++){
    #pragma unroll
    for (int j=0;j<NI;j++){
      #pragma unroll
      for (int r=0;r<4;r++){
        int m = m0 + wm0 + i*16 + l16*4 + r;
        int n = n0 + wn0 + j*16 + l15;
        float v = acc[i][j][r];
        if (EPI==1){
          v += bias[n];
          v = (v>20.f) ? v : log1pf(__expf(v));
          C[(long)m*ldc + n] = v;
        } else if (EPI==2){
          v += bias[n];
          int bb = m>>8, np_ = m&255, p = n>>8, dp = n&255;
          C[((long)(bb*1024 + np_*4 + p))*256 + dp] = v;
        } else {
          C[(long)m*ldc + n] = v;
        }
      }
    }
  }
}

// ---------------- split-K reduce for xproj + bf16 dt side-product
__global__ __launch_bounds__(256) void xreduce_k(const float* __restrict__ part,
    float* __restrict__ xdbl, u16* __restrict__ dtbf){
  int idx = blockIdx.x*256 + threadIdx.x;   // 131072
  int d = idx >> 16, off = idx & 65535;
  float s = 0.f;
  #pragma unroll
  for (int kc=0; kc<8; ++kc) s += part[((d*8+kc)<<16) + off];
  xdbl[idx] = s;
  int col = off & 63;
  if (col < 32){
    int m = off >> 6;
    dtbf[((long)d*MT + m)*32 + col] = f2bf(s);
  }
}

// ---------------- causal depthwise conv + bias + silu; 4 l-outputs per thread
__global__ __launch_bounds__(256) void conv_silu_k(const float* __restrict__ xz,
    const float* __restrict__ cw, const float* __restrict__ cb,
    float* __restrict__ u, u16* __restrict__ ubf){
  int idx = blockIdx.x*256 + threadIdx.x;   // 2*MT*DI/4 = 524288
  int e = idx & (DI-1);
  int grp = idx >> 10;          // 512 groups: dir(1) | b(2) | lg(6)
  int dir = grp >> 8;
  int b   = (grp >> 6) & 3;
  int l0  = (grp & 63) * 4;
  long dm0 = (long)dir*MT + b*LL + l0;
  const float* w = cw + ((long)dir*DI + e)*4;
  float w0=w[0], w1=w[1], w2=w[2], w3=w[3];
  float bias = cb[dir*DI + e];
  const float* src = xz + dm0*2048 + e;     // row l0
  float vb[7];
  #pragma unroll
  for (int j=0;j<7;j++){
    int l = l0 - 3 + j;
    vb[j] = (l >= 0) ? src[(long)(j-3)*2048] : 0.f;
  }
  #pragma unroll
  for (int j=0;j<4;j++){
    float acc = bias;
    acc = fmaf(w0, vb[j],   acc);
    acc = fmaf(w1, vb[j+1], acc);
    acc = fmaf(w2, vb[j+2], acc);
    acc = fmaf(w3, vb[j+3], acc);
    float v = acc * sigmoidf_(acc);
    u  [(dm0+j)*DI + e] = v;
    ubf[(dm0+j)*DI + e] = f2bf(v);
  }
}

// ---------------- selective scan; 4x8 sub-blocked inner loop (ds_read2-friendly)
__global__ __launch_bounds__(256) void scan_k(
    const float* __restrict__ delta, const float* __restrict__ u,
    const float* __restrict__ xz, const float* __restrict__ xdbl,
    const float* __restrict__ A_log, const float* __restrict__ Dp,
    u16* __restrict__ ygbf)
{
  int t = threadIdx.x;
  int n = t & 15, el = t >> 4;
  int ec = blockIdx.x, b = blockIdx.y, dir = blockIdx.z;
  int e0 = ec*16;
  int e = e0 + el;
  float Av = -__expf(A_log[((long)dir*DI + e)*16 + n]);
  float Dv = Dp[dir*DI + e];
  long mbase = (long)dir*MT + b*LL;
  const float* dp_ = delta + mbase*DI;
  const float* up_ = u     + mbase*DI;
  const float* zp_ = xz    + mbase*2048 + 1024;
  const float* bc_ = xdbl  + mbase*64 + 32;
  u16* yp_ = ygbf + mbase*DI;

  __shared__ float sDU[2][CL][32];
  __shared__ float sBC[2][CL][32];
  __shared__ float sy[CL][16];

  int lb  = t >> 3,        jb = (t & 7) * 4;
  int tt  = t & 127;
  int ld_ = tt >> 2,       ed = (tt & 3) * 4;

  float4 pbc, pdu;
  auto load_pre = [&](int c){
    long l0 = (long)c*CL;
    pbc = *(const float4*)&bc_[(l0+lb)*64 + jb];
    pdu = (t < 128) ? *(const float4*)&dp_[(l0+ld_)*DI + e0 + ed]
                    : *(const float4*)&up_[(l0+ld_)*DI + e0 + ed];
  };
  auto write_pre = [&](int buf){
    *(float4*)&sBC[buf][lb][jb] = pbc;
    if (t < 128) *(float4*)&sDU[buf][ld_][ed]      = pdu;
    else         *(float4*)&sDU[buf][ld_][16+ed]   = pdu;
  };

  load_pre(0);
  write_pre(0);
  load_pre(1);
  __syncthreads();

  float h = 0.f;
  for (int c = 0; c < NCH; ++c){
    int cur = c & 1;
    float4 zc;
    if (t < 128) zc = *(const float4*)&zp_[((long)c*CL + ld_)*2048 + e0 + ed];

    const float* du = &sDU[cur][0][el];
    const float* bc = &sBC[cur][0][n];
    #pragma unroll
    for (int c8 = 0; c8 < 4; ++c8){
      const float* du8 = du + c8*256;    // 8 l-steps, dword offsets <= 240
      const float* bc8 = bc + c8*256;
      #pragma unroll
      for (int l8 = 0; l8 < 8; ++l8){
        float dv = du8[l8*32],  uv = du8[l8*32 + 16];
        float Bv = bc8[l8*32],  Cv = bc8[l8*32 + 16];
        float dA = __expf(dv*Av);
        h = fmaf(dA, h, dv*uv*Bv);
        float yc = sum16_dpp(h*Cv);
        if (n==0) sy[c8*8+l8][el] = yc + uv*Dv;
      }
    }
    __syncthreads();
    if (c+1 < NCH){
      write_pre(cur^1);
      if (c+2 < NCH) load_pre(c+2);
    }
    if (t < 128){
      float4 y4 = *(const float4*)&sy[ld_][ed];
      float gx = zc.x*sigmoidf_(zc.x), gy = zc.y*sigmoidf_(zc.y);
      float gz = zc.z*sigmoidf_(zc.z), gw = zc.w*sigmoidf_(zc.w);
      ushort4 o; o.x=f2bf(y4.x*gx); o.y=f2bf(y4.y*gy); o.z=f2bf(y4.z*gz); o.w=f2bf(y4.w*gw);
      *(ushort4*)&yp_[((long)c*CL + ld_)*DI + e0 + ed] = o;
    }
    __syncthreads();
  }
}

extern "C" void kernel_launch(void* const* d_in, const int* in_sizes, int n_in,
                              void* d_out, int out_size, void* d_ws, size_t ws_size,
                              hipStream_t stream){
  const float* ts   = (const float*)d_in[0];
  const float* ew   = (const float*)d_in[2];
  const float* eb   = (const float*)d_in[3];
  const float* nw   = (const float*)d_in[4];
  const float* inw  = (const float*)d_in[5];
  const float* cw   = (const float*)d_in[6];
  const float* cb   = (const float*)d_in[7];
  const float* xpw  = (const float*)d_in[8];
  const float* dtw  = (const float*)d_in[9];
  const float* dtb  = (const float*)d_in[10];
  const float* alog = (const float*)d_in[11];
  const float* dpp  = (const float*)d_in[12];
  const float* outw = (const float*)d_in[13];
  const float* pw   = (const float*)d_in[14];
  const float* pb   = (const float*)d_in[15];
  float* out = (float*)d_out;

  float* ws   = (float*)d_ws;
  float* x    = ws;                  // 524288
  float* xz   = ws + 524288;         // 4194304
  float* u    = ws + 4718592;        // 2097152
  float* xdbl = ws + 6815744;        // 131072
  float* delta= ws + 6946816;        // 2097152
  float* yout = ws + 9043968;        // 1048576
  float* xpart= ws + 10092544;       // 1048576 (2*8*65536)
  u16* ub     = (u16*)(ws + 11141120);
  u16* xn_bf  = ub;                  // 1048576 (both dirs)
  u16* u_bf   = ub + 1048576;        // 2097152
  u16* yg_bf  = ub + 3145728;        // 2097152
  u16* x_bf   = ub + 5242880;        // 524288
  u16* dt_bf  = ub + 5767168;        // 65536
  u16* wb     = ub + 5832704;        // 27262976 total bf16 weights
  u16* wb_in  = wb;                  // 16777216
  u16* wb_out = wb + 16777216;       // 8388608
  u16* wb_xp  = wb + 25165824;       // 1048576
  u16* wb_dt  = wb + 26214400;       // 524288
  u16* wb_pj  = wb + 26738688;       // 524288

  dim3 blk(256);

  embed_k<<<MT*DM/256, blk, 0, stream>>>(ts, ew, eb, x);
  wcastall_k<<<6656, blk, 0, stream>>>(inw, outw, xpw, dtw, pw, wb);

  for (int i=0;i<NLAYER;i++){
    rmscomb_k<<<MT, blk, 0, stream>>>(x, i ? yout : nullptr, nw + i*DM,
        xn_bf, xn_bf + MT*DM);
    // in_proj: (1024x512)@(2048x512)^T -> xz fp32; 64x128 tiles, 512 blocks
    mfma_nt<64,128,1,0><<<dim3(16,16,2), blk, 0, stream>>>(
        xn_bf, DM, (long)MT*DM, wb_in + (long)i*2097152, DM, 1048576,
        nullptr, 0, xz, 2048, (long)MT*2048, MT, 2048, DM);
    conv_silu_k<<<2048, blk, 0, stream>>>(xz, cw + (long)i*2*DI*4, cb + i*2*DI, u, u_bf);
    // xproj: (1024x1024)@(64x1024)^T split-K=8, 64x64 tiles, 256 blocks
    mfma_nt<64,64,8,0><<<dim3(1,16,16), blk, 0, stream>>>(
        u_bf, DI, (long)MT*DI, wb_xp + (long)i*131072, DI, 65536,
        nullptr, 0, xpart, 64, 0, MT, 64, DI);
    xreduce_k<<<512, blk, 0, stream>>>(xpart, xdbl, dt_bf);
    // delta = softplus(dt @ dt_w^T + dt_b)  (bf16 MFMA, K=32)
    mfma_nt<128,64,1,1><<<dim3(16,8,2), blk, 0, stream>>>(
        dt_bf, DTR, (long)MT*DTR, wb_dt + (long)i*65536, DTR, 32768,
        dtb + (long)i*2*DI, DI, delta, DI, (long)MT*DI, MT, DI, DTR);
    scan_k<<<dim3(64, BS, 2), blk, 0, stream>>>(delta, u, xz, xdbl,
        alog + (long)i*2*DI*16, dpp + i*2*DI, yg_bf);
    // out_proj: (1024x1024)@(512x1024)^T; 64x64 tiles, 256 blocks
    mfma_nt<64,64,1,0><<<dim3(8,16,2), blk, 0, stream>>>(
        yg_bf, DI, (long)MT*DI, wb_out + (long)i*1048576, DI, 524288,
        nullptr, 0, yout, DM, (long)MT*DM, MT, DM, DI);
  }
  combcast_k<<<MT*DM/4/256, blk, 0, stream>>>(x, yout, x_bf);
  // final proj + bias + scatter; 64x64 tiles, 256 blocks
  mfma_nt<64,64,1,2><<<dim3(16,16,1), blk, 0, stream>>>(
      x_bf, DM, 0, wb_pj, DM, 0, pb, 0, out, 1024, 0, MT, 1024, DM);
}

// Round 9
// 796.762 us; speedup vs baseline: 1.4299x; 1.0538x over previous
//
#include <hip/hip_runtime.h>
#include <hip/hip_bf16.h>

#define DM 512      // d_model
#define DI 1024     // d_inner
#define DSTATE 16
#define DTR 32      // dt_rank
#define NLAYER 8
#define BS 4
#define LL 256      // tokens per batch (F*NP)
#define MT 1024     // BS*LL total tokens
#define DPROJ 256
#define CL 32       // scan chunk length
#define NCH (LL/CL)

typedef unsigned short u16;
typedef __attribute__((ext_vector_type(8))) short short8;
typedef __attribute__((ext_vector_type(4))) float f32x4;

__device__ __forceinline__ float sigmoidf_(float x){ return 1.f/(1.f+__expf(-x)); }

// fp32 -> bf16 round-to-nearest-even (finite inputs)
__device__ __forceinline__ u16 f2bf(float f){
  unsigned u = __float_as_uint(f);
  u = (u + 0x7FFF + ((u>>16)&1)) >> 16;
  return (u16)u;
}
__device__ __forceinline__ float bf2f(u16 v){
  return __uint_as_float(((unsigned)v) << 16);
}

// VALU-pipe 16-lane sum via DPP row rotations
template<int CTRL>
__device__ __forceinline__ float dpp_ror_add(float x){
  int y = __builtin_amdgcn_update_dpp(0, __float_as_int(x), CTRL, 0xF, 0xF, false);
  return x + __int_as_float(y);
}
__device__ __forceinline__ float sum16_dpp(float x){
  x = dpp_ror_add<0x128>(x);
  x = dpp_ror_add<0x124>(x);
  x = dpp_ror_add<0x122>(x);
  x = dpp_ror_add<0x121>(x);
  return x;
}

// ---------------- patch embed
__global__ __launch_bounds__(256) void embed_k(const float* __restrict__ ts,
    const float* __restrict__ ew, const float* __restrict__ eb, float* __restrict__ x){
  int idx = blockIdx.x*256 + threadIdx.x;     // MT*DM
  int m = idx >> 9, d = idx & 511;
  int b = m >> 8, np_ = m & 255;
  const float* t0 = ts + b*1024 + np_*4;
  float acc = eb[d];
  #pragma unroll
  for (int p=0;p<4;p++) acc = fmaf(t0[p], ew[d*4+p], acc);
  x[idx] = acc;
}

// ---------------- cast ALL weights to bf16 once; coalesced float4->ushort4
__global__ __launch_bounds__(256) void wcastall_k(
    const float* __restrict__ w_in, const float* __restrict__ w_out,
    const float* __restrict__ w_xp, const float* __restrict__ w_pj,
    u16* __restrict__ dst){
  int t = blockIdx.x*256 + threadIdx.x;   // 6684672 float4s
  long e4 = (long)t*4;
  const float* src; long o;
  if      (e4 < 16777216) { src = w_in;  o = e4; }
  else if (e4 < 25165824) { src = w_out; o = e4 - 16777216; }
  else if (e4 < 26214400) { src = w_xp;  o = e4 - 25165824; }
  else                    { src = w_pj;  o = e4 - 26214400; }
  float4 v = *(const float4*)(src + o);
  ushort4 r; r.x=f2bf(v.x); r.y=f2bf(v.y); r.z=f2bf(v.z); r.w=f2bf(v.w);
  *(ushort4*)(dst + e4) = r;
}

// ---------------- fused (residual combine) + rmsnorm -> bf16 normal+flipped
__global__ __launch_bounds__(256) void rmscomb_k(float* __restrict__ x,
    const float* __restrict__ yout,   // nullptr for layer 0
    const float* __restrict__ nw, u16* __restrict__ xnbf, u16* __restrict__ xnfbf){
  int m = blockIdx.x, t = threadIdx.x;
  int b = m>>8, l = m&255, mf = (b<<8)+(255-l);
  float2 v = *(const float2*)&x[(long)m*DM + t*2];
  if (yout){
    float2 f = *(const float2*)&yout[(long)m*DM + t*2];
    float2 g = *(const float2*)&yout[(long)MT*DM + (long)mf*DM + t*2];
    v.x += f.x + g.x; v.y += f.y + g.y;
    *(float2*)&x[(long)m*DM + t*2] = v;
  }
  float ss = v.x*v.x + v.y*v.y;
  ss += __shfl_down(ss,32); ss += __shfl_down(ss,16); ss += __shfl_down(ss,8);
  ss += __shfl_down(ss,4);  ss += __shfl_down(ss,2);  ss += __shfl_down(ss,1);
  __shared__ float ps[4];
  if ((t&63)==0) ps[t>>6] = ss;
  __syncthreads();
  float tot = ps[0]+ps[1]+ps[2]+ps[3];
  float rs = rsqrtf(tot*(1.f/DM) + 1e-5f);
  ushort2 o; o.x = f2bf(v.x*rs*nw[t*2]); o.y = f2bf(v.y*rs*nw[t*2+1]);
  *(ushort2*)&xnbf [(long)m *DM + t*2] = o;
  *(ushort2*)&xnfbf[(long)mf*DM + t*2] = o;
}

// ---------------- final combine + cast to bf16
__global__ __launch_bounds__(256) void combcast_k(const float* __restrict__ x,
    const float* __restrict__ yout, u16* __restrict__ xbf){
  int idx = blockIdx.x*256 + threadIdx.x;   // MT*DM/4
  int m = idx >> 7, c4 = idx & 127;
  int b = m>>8, l = m&255, mf = (b<<8)+(255-l);
  float4 r = ((const float4*)x)[idx];
  float4 f = ((const float4*)yout)[idx];
  float4 g = ((const float4*)(yout + (long)MT*DM))[(long)mf*128 + c4];
  ushort4 o;
  o.x = f2bf(r.x + f.x + g.x); o.y = f2bf(r.y + f.y + g.y);
  o.z = f2bf(r.z + f.z + g.z); o.w = f2bf(r.w + f.w + g.w);
  ((ushort4*)xbf)[idx] = o;
}

// ---------------- bf16 MFMA GEMM: C = A @ W^T
// SPLITK>1: z = dir*SPLITK+kc, fp32 partials at C + z*M*N.
// EPI: 0 plain | 2 final scatter+bias
template<int BM,int BN,int SPLITK,int EPI>
__global__ __launch_bounds__(256) void mfma_nt(
    const u16* __restrict__ A, int lda, long sA,
    const u16* __restrict__ W, int ldw, long sW,
    const float* __restrict__ bias,
    float* __restrict__ C, int ldc, long sC,
    int M, int N, int K)
{
  constexpr int WM = BM/2, WN = BN/2;
  constexpr int MI = WM/16, NI = WN/16;
  int z = blockIdx.z;
  int dir = z / SPLITK, kc = z % SPLITK;
  int Klen = K / SPLITK;
  int kbase = kc * Klen;
  A += (long)dir * sA;
  W += (long)dir * sW;
  if (SPLITK > 1) C += (long)z * M * N; else C += (long)dir * sC;

  __shared__ u16 Al[BM*32];
  __shared__ u16 Wl[BN*32];
  int tid = threadIdx.x;
  int lane = tid & 63;
  int wave = tid >> 6;
  int wm0 = (wave>>1)*WM, wn0 = (wave&1)*WN;
  int m0 = blockIdx.y*BM, n0 = blockIdx.x*BN;
  int l16 = lane>>4, l15 = lane&15;

  f32x4 acc[MI][NI] = {};

  for (int k0=0; k0<Klen; k0+=32){
    #pragma unroll
    for (int it=0; it<BM*4/256; ++it){
      int ch = it*256 + tid;
      int row = ch % BM, kk = ch / BM;
      const u16* g = A + (long)(m0+row)*lda + kbase + k0 + kk*8;
      __builtin_amdgcn_global_load_lds(
          (const __attribute__((address_space(1))) void*)g,
          (__attribute__((address_space(3))) void*)(Al + ch*8), 16, 0, 0);
    }
    #pragma unroll
    for (int it=0; it<BN*4/256; ++it){
      int ch = it*256 + tid;
      int row = ch % BN, kk = ch / BN;
      const u16* g = W + (long)(n0+row)*ldw + kbase + k0 + kk*8;
      __builtin_amdgcn_global_load_lds(
          (const __attribute__((address_space(1))) void*)g,
          (__attribute__((address_space(3))) void*)(Wl + ch*8), 16, 0, 0);
    }
    __syncthreads();
    short8 a[MI], b[NI];
    #pragma unroll
    for (int i=0;i<MI;i++)
      a[i] = *(const short8*)&Al[(l16*BM + wm0 + i*16 + l15)*8];
    #pragma unroll
    for (int j=0;j<NI;j++)
      b[j] = *(const short8*)&Wl[(l16*BN + wn0 + j*16 + l15)*8];
    #pragma unroll
    for (int i=0;i<MI;i++)
      #pragma unroll
      for (int j=0;j<NI;j++)
        acc[i][j] = __builtin_amdgcn_mfma_f32_16x16x32_bf16(a[i], b[j], acc[i][j], 0,0,0);
    __syncthreads();
  }
  #pragma unroll
  for (int i=0;i<MI;i++){
    #pragma unroll
    for (int j=0;j<NI;j++){
      #pragma unroll
      for (int r=0;r<4;r++){
        int m = m0 + wm0 + i*16 + l16*4 + r;
        int n = n0 + wn0 + j*16 + l15;
        float v = acc[i][j][r];
        if (EPI==2){
          v += bias[n];
          int bb = m>>8, np_ = m&255, p = n>>8, dp = n&255;
          C[((long)(bb*1024 + np_*4 + p))*256 + dp] = v;
        } else {
          C[(long)m*ldc + n] = v;
        }
      }
    }
  }
}

// ---------------- split-K reduce for xproj
__global__ __launch_bounds__(256) void xreduce_k(const float* __restrict__ part,
    float* __restrict__ xdbl){
  int idx = blockIdx.x*256 + threadIdx.x;   // 131072
  int d = idx >> 16, off = idx & 65535;
  float s = 0.f;
  #pragma unroll
  for (int kc=0; kc<8; ++kc) s += part[((d*8+kc)<<16) + off];
  xdbl[idx] = s;
}

// ---------------- causal depthwise conv + bias + silu -> bf16 u only
__global__ __launch_bounds__(256) void conv_silu_k(const float* __restrict__ xz,
    const float* __restrict__ cw, const float* __restrict__ cb,
    u16* __restrict__ ubf){
  int idx = blockIdx.x*256 + threadIdx.x;   // 2*MT*DI/4 = 524288
  int e = idx & (DI-1);
  int grp = idx >> 10;          // 512 groups: dir(1) | b(2) | lg(6)
  int dir = grp >> 8;
  int b   = (grp >> 6) & 3;
  int l0  = (grp & 63) * 4;
  long dm0 = (long)dir*MT + b*LL + l0;
  const float* w = cw + ((long)dir*DI + e)*4;
  float w0=w[0], w1=w[1], w2=w[2], w3=w[3];
  float bias = cb[dir*DI + e];
  const float* src = xz + dm0*2048 + e;     // row l0
  float vb[7];
  #pragma unroll
  for (int j=0;j<7;j++){
    int l = l0 - 3 + j;
    vb[j] = (l >= 0) ? src[(long)(j-3)*2048] : 0.f;
  }
  #pragma unroll
  for (int j=0;j<4;j++){
    float acc = bias;
    acc = fmaf(w0, vb[j],   acc);
    acc = fmaf(w1, vb[j+1], acc);
    acc = fmaf(w2, vb[j+2], acc);
    acc = fmaf(w3, vb[j+3], acc);
    float v = acc * sigmoidf_(acc);
    ubf[(dm0+j)*DI + e] = f2bf(v);
  }
}

// ---------------- selective scan with fused delta (softplus(xdbl[:, :32]@dtw^T+dtb))
// block = 256 threads = (el 0..15)x(n 0..15); grid (64, B, 2)
__global__ __launch_bounds__(256) void scan_k(
    const u16* __restrict__ ubf, const float* __restrict__ xz,
    const float* __restrict__ xdbl, const float* __restrict__ dtw,
    const float* __restrict__ dtb, const float* __restrict__ A_log,
    const float* __restrict__ Dp, u16* __restrict__ ygbf)
{
  int t = threadIdx.x;
  int n = t & 15, el = t >> 4;
  int ec = blockIdx.x, b = blockIdx.y, dir = blockIdx.z;
  int e0 = ec*16, e = e0 + el;
  float Av = -__expf(A_log[((long)dir*DI + e)*16 + n]);
  float Dv = Dp[dir*DI + e];
  long mbase = (long)dir*MT + b*LL;
  const u16*  up_ = ubf + mbase*DI;
  const float* zp_ = xz + mbase*2048 + 1024;
  const float* xd_ = xdbl + mbase*64;
  u16* yp_ = ygbf + mbase*DI;

  // dtw row (e0+n) in regs for the delta-compute phase
  float wrow[32];
  {
    const float* wr = dtw + ((long)dir*DI + e0 + n)*32;
    #pragma unroll
    for (int r4=0;r4<8;r4++) *(float4*)&wrow[r4*4] = *(const float4*)&wr[r4*4];
  }
  float dtbv = dtb[dir*DI + e0 + n];

  __shared__ float sdt[2][CL][32];   // xdbl cols 0..31
  __shared__ float sBC[2][CL][32];   // B cols 0..15, C cols 16..31
  __shared__ float sU [2][CL][16];
  __shared__ float sD [CL][16];
  __shared__ float sy [CL][16];

  float4 xv0, xv1; ushort4 uvv;
  auto load_pre = [&](int c){
    long l0 = (long)c*CL;
    int f0 = t, f1 = t + 256;   // 512 float4s = 32 rows x 16
    xv0 = *(const float4*)&xd_[(l0 + (f0>>4))*64 + (f0&15)*4];
    xv1 = *(const float4*)&xd_[(l0 + (f1>>4))*64 + (f1&15)*4];
    if (t < 128) uvv = *(const ushort4*)&up_[(l0 + (t>>2))*DI + e0 + (t&3)*4];
  };
  auto write_pre = [&](int buf){
    {
      int row = t>>4, c4 = (t&15)*4;
      if (c4 < 32) *(float4*)&sdt[buf][row][c4] = xv0;
      else         *(float4*)&sBC[buf][row][c4-32] = xv0;
    }
    {
      int f1 = t + 256;
      int row = f1>>4, c4 = (f1&15)*4;
      if (c4 < 32) *(float4*)&sdt[buf][row][c4] = xv1;
      else         *(float4*)&sBC[buf][row][c4-32] = xv1;
    }
    if (t < 128){
      float4 uf;
      uf.x = bf2f(uvv.x); uf.y = bf2f(uvv.y); uf.z = bf2f(uvv.z); uf.w = bf2f(uvv.w);
      *(float4*)&sU[buf][t>>2][(t&3)*4] = uf;
    }
  };

  load_pre(0);
  write_pre(0);
  load_pre(1);
  __syncthreads();

  float h = 0.f;
  for (int c = 0; c < NCH; ++c){
    int cur = c & 1;
    // delta for this chunk: thread computes 2 values at (l, e0+n)
    #pragma unroll
    for (int j=0;j<2;j++){
      int l = (t>>4)*2 + j;
      float acc = dtbv;
      #pragma unroll
      for (int r4=0;r4<8;r4++){
        float4 d4 = *(const float4*)&sdt[cur][l][r4*4];
        acc = fmaf(d4.x, wrow[r4*4],   acc);
        acc = fmaf(d4.y, wrow[r4*4+1], acc);
        acc = fmaf(d4.z, wrow[r4*4+2], acc);
        acc = fmaf(d4.w, wrow[r4*4+3], acc);
      }
      acc = (acc>20.f) ? acc : log1pf(__expf(acc));
      sD[l][n] = acc;
    }
    // issue z load early (consumed in epilogue)
    float4 zc;
    if (t < 128) zc = *(const float4*)&zp_[((long)c*CL + (t>>2))*2048 + e0 + (t&3)*4];
    __syncthreads();   // sD visible

    const float* pD  = &sD[0][el];
    const float* pU  = &sU[cur][0][el];
    const float* pBC = &sBC[cur][0][n];
    #pragma unroll
    for (int c8 = 0; c8 < 4; ++c8){
      const float* pD8  = pD  + c8*128;
      const float* pU8  = pU  + c8*128;
      const float* pBC8 = pBC + c8*256;
      #pragma unroll
      for (int l8 = 0; l8 < 8; ++l8){
        float dv = pD8[l8*16];
        float uv = pU8[l8*16];
        float Bv = pBC8[l8*32], Cv = pBC8[l8*32 + 16];
        float dA = __expf(dv*Av);
        h = fmaf(dA, h, dv*uv*Bv);
        float yc = sum16_dpp(h*Cv);
        if (n==0) sy[c8*8+l8][el] = yc + uv*Dv;
      }
    }
    __syncthreads();   // buffers cur & sD free; sy complete
    if (c+1 < NCH){
      write_pre(cur^1);
      if (c+2 < NCH) load_pre(c+2);
    }
    if (t < 128){
      float4 y4 = *(const float4*)&sy[t>>2][(t&3)*4];
      float gx = zc.x*sigmoidf_(zc.x), gy = zc.y*sigmoidf_(zc.y);
      float gz = zc.z*sigmoidf_(zc.z), gw = zc.w*sigmoidf_(zc.w);
      ushort4 o; o.x=f2bf(y4.x*gx); o.y=f2bf(y4.y*gy); o.z=f2bf(y4.z*gz); o.w=f2bf(y4.w*gw);
      *(ushort4*)&yp_[((long)c*CL + (t>>2))*DI + e0 + (t&3)*4] = o;
    }
    __syncthreads();
  }
}

extern "C" void kernel_launch(void* const* d_in, const int* in_sizes, int n_in,
                              void* d_out, int out_size, void* d_ws, size_t ws_size,
                              hipStream_t stream){
  const float* ts   = (const float*)d_in[0];
  const float* ew   = (const float*)d_in[2];
  const float* eb   = (const float*)d_in[3];
  const float* nw   = (const float*)d_in[4];
  const float* inw  = (const float*)d_in[5];
  const float* cw   = (const float*)d_in[6];
  const float* cb   = (const float*)d_in[7];
  const float* xpw  = (const float*)d_in[8];
  const float* dtw  = (const float*)d_in[9];
  const float* dtb  = (const float*)d_in[10];
  const float* alog = (const float*)d_in[11];
  const float* dpp  = (const float*)d_in[12];
  const float* outw = (const float*)d_in[13];
  const float* pw   = (const float*)d_in[14];
  const float* pb   = (const float*)d_in[15];
  float* out = (float*)d_out;

  float* ws   = (float*)d_ws;
  float* x    = ws;                  // 524288
  float* xz   = ws + 524288;         // 4194304
  float* xdbl = ws + 4718592;        // 131072
  float* yout = ws + 4849664;        // 1048576
  float* xpart= ws + 5898240;        // 1048576 (2*8*65536)
  u16* ub     = (u16*)(ws + 6946816);
  u16* xn_bf  = ub;                  // 1048576 (both dirs)
  u16* u_bf   = ub + 1048576;        // 2097152
  u16* yg_bf  = ub + 3145728;        // 2097152
  u16* x_bf   = ub + 5242880;        // 524288
  u16* wb     = ub + 5767168;        // 26738688 bf16 weights (in|out|xp|pj)
  u16* wb_in  = wb;                  // 16777216
  u16* wb_out = wb + 16777216;       // 8388608
  u16* wb_xp  = wb + 25165824;       // 1048576
  u16* wb_pj  = wb + 26214400;       // 524288

  dim3 blk(256);

  embed_k<<<MT*DM/256, blk, 0, stream>>>(ts, ew, eb, x);
  wcastall_k<<<26112, blk, 0, stream>>>(inw, outw, xpw, pw, wb);

  for (int i=0;i<NLAYER;i++){
    rmscomb_k<<<MT, blk, 0, stream>>>(x, i ? yout : nullptr, nw + i*DM,
        xn_bf, xn_bf + MT*DM);
    // in_proj: (1024x512)@(2048x512)^T -> xz fp32; 64x128 tiles, 512 blocks
    mfma_nt<64,128,1,0><<<dim3(16,16,2), blk, 0, stream>>>(
        xn_bf, DM, (long)MT*DM, wb_in + (long)i*2097152, DM, 1048576,
        nullptr, xz, 2048, (long)MT*2048, MT, 2048, DM);
    conv_silu_k<<<2048, blk, 0, stream>>>(xz, cw + (long)i*2*DI*4, cb + i*2*DI, u_bf);
    // xproj: (1024x1024)@(64x1024)^T split-K=8, 64x64 tiles, 256 blocks
    mfma_nt<64,64,8,0><<<dim3(1,16,16), blk, 0, stream>>>(
        u_bf, DI, (long)MT*DI, wb_xp + (long)i*131072, DI, 65536,
        nullptr, xpart, 64, 0, MT, 64, DI);
    xreduce_k<<<512, blk, 0, stream>>>(xpart, xdbl);
    // scan with fused fp32 delta-GEMM
    scan_k<<<dim3(64, BS, 2), blk, 0, stream>>>(u_bf, xz, xdbl,
        dtw + (long)i*2*DI*DTR, dtb + (long)i*2*DI,
        alog + (long)i*2*DI*16, dpp + i*2*DI, yg_bf);
    // out_proj: (1024x1024)@(512x1024)^T; 64x64 tiles, 256 blocks
    mfma_nt<64,64,1,0><<<dim3(8,16,2), blk, 0, stream>>>(
        yg_bf, DI, (long)MT*DI, wb_out + (long)i*1048576, DI, 524288,
        nullptr, yout, DM, (long)MT*DM, MT, DM, DI);
  }
  combcast_k<<<MT*DM/4/256, blk, 0, stream>>>(x, yout, x_bf);
  // final proj + bias + scatter; 64x64 tiles, 256 blocks
  mfma_nt<64,64,1,2><<<dim3(16,16,1), blk, 0, stream>>>(
      x_bf, DM, 0, wb_pj, DM, 0, pb, out, 1024, 0, MT, 1024, DM);
}

// Round 10
// 766.424 us; speedup vs baseline: 1.4865x; 1.0396x over previous
//
#include <hip/hip_runtime.h>
#include <hip/hip_bf16.h>

#define DM 512      // d_model
#define DI 1024     // d_inner
#define DSTATE 16
#define DTR 32      // dt_rank
#define NLAYER 8
#define BS 4
#define LL 256      // tokens per batch (F*NP)
#define MT 1024     // BS*LL total tokens
#define DPROJ 256
#define CL 32       // scan chunk length
#define NCH (LL/CL)
#define SP 20       // padded LDS row stride (floats) for 16-wide tiles

typedef unsigned short u16;
typedef __attribute__((ext_vector_type(8))) short short8;
typedef __attribute__((ext_vector_type(4))) float f32x4;

__device__ __forceinline__ float sigmoidf_(float x){ return 1.f/(1.f+__expf(-x)); }

// fp32 -> bf16 round-to-nearest-even (finite inputs)
__device__ __forceinline__ u16 f2bf(float f){
  unsigned u = __float_as_uint(f);
  u = (u + 0x7FFF + ((u>>16)&1)) >> 16;
  return (u16)u;
}
__device__ __forceinline__ float bf2f(u16 v){
  return __uint_as_float(((unsigned)v) << 16);
}

// VALU-pipe 16-lane sum via DPP row rotations
template<int CTRL>
__device__ __forceinline__ float dpp_ror_add(float x){
  int y = __builtin_amdgcn_update_dpp(0, __float_as_int(x), CTRL, 0xF, 0xF, false);
  return x + __int_as_float(y);
}
__device__ __forceinline__ float sum16_dpp(float x){
  x = dpp_ror_add<0x128>(x);
  x = dpp_ror_add<0x124>(x);
  x = dpp_ror_add<0x122>(x);
  x = dpp_ror_add<0x121>(x);
  return x;
}

// ---------------- patch embed
__global__ __launch_bounds__(256) void embed_k(const float* __restrict__ ts,
    const float* __restrict__ ew, const float* __restrict__ eb, float* __restrict__ x){
  int idx = blockIdx.x*256 + threadIdx.x;     // MT*DM
  int m = idx >> 9, d = idx & 511;
  int b = m >> 8, np_ = m & 255;
  const float* t0 = ts + b*1024 + np_*4;
  float acc = eb[d];
  #pragma unroll
  for (int p=0;p<4;p++) acc = fmaf(t0[p], ew[d*4+p], acc);
  x[idx] = acc;
}

// ---------------- cast ALL weights to bf16 once; coalesced float4->ushort4
__global__ __launch_bounds__(256) void wcastall_k(
    const float* __restrict__ w_in, const float* __restrict__ w_out,
    const float* __restrict__ w_xp, const float* __restrict__ w_pj,
    u16* __restrict__ dst){
  int t = blockIdx.x*256 + threadIdx.x;   // 6684672 float4s
  long e4 = (long)t*4;
  const float* src; long o;
  if      (e4 < 16777216) { src = w_in;  o = e4; }
  else if (e4 < 25165824) { src = w_out; o = e4 - 16777216; }
  else if (e4 < 26214400) { src = w_xp;  o = e4 - 25165824; }
  else                    { src = w_pj;  o = e4 - 26214400; }
  float4 v = *(const float4*)(src + o);
  ushort4 r; r.x=f2bf(v.x); r.y=f2bf(v.y); r.z=f2bf(v.z); r.w=f2bf(v.w);
  *(ushort4*)(dst + e4) = r;
}

// ---------------- fused (residual combine) + rmsnorm -> bf16 normal+flipped
__global__ __launch_bounds__(256) void rmscomb_k(float* __restrict__ x,
    const float* __restrict__ yout,   // nullptr for layer 0
    const float* __restrict__ nw, u16* __restrict__ xnbf, u16* __restrict__ xnfbf){
  int m = blockIdx.x, t = threadIdx.x;
  int b = m>>8, l = m&255, mf = (b<<8)+(255-l);
  float2 v = *(const float2*)&x[(long)m*DM + t*2];
  if (yout){
    float2 f = *(const float2*)&yout[(long)m*DM + t*2];
    float2 g = *(const float2*)&yout[(long)MT*DM + (long)mf*DM + t*2];
    v.x += f.x + g.x; v.y += f.y + g.y;
    *(float2*)&x[(long)m*DM + t*2] = v;
  }
  float ss = v.x*v.x + v.y*v.y;
  ss += __shfl_down(ss,32); ss += __shfl_down(ss,16); ss += __shfl_down(ss,8);
  ss += __shfl_down(ss,4);  ss += __shfl_down(ss,2);  ss += __shfl_down(ss,1);
  __shared__ float ps[4];
  if ((t&63)==0) ps[t>>6] = ss;
  __syncthreads();
  float tot = ps[0]+ps[1]+ps[2]+ps[3];
  float rs = rsqrtf(tot*(1.f/DM) + 1e-5f);
  ushort2 o; o.x = f2bf(v.x*rs*nw[t*2]); o.y = f2bf(v.y*rs*nw[t*2+1]);
  *(ushort2*)&xnbf [(long)m *DM + t*2] = o;
  *(ushort2*)&xnfbf[(long)mf*DM + t*2] = o;
}

// ---------------- final combine + cast to bf16
__global__ __launch_bounds__(256) void combcast_k(const float* __restrict__ x,
    const float* __restrict__ yout, u16* __restrict__ xbf){
  int idx = blockIdx.x*256 + threadIdx.x;   // MT*DM/4
  int m = idx >> 7, c4 = idx & 127;
  int b = m>>8, l = m&255, mf = (b<<8)+(255-l);
  float4 r = ((const float4*)x)[idx];
  float4 f = ((const float4*)yout)[idx];
  float4 g = ((const float4*)(yout + (long)MT*DM))[(long)mf*128 + c4];
  ushort4 o;
  o.x = f2bf(r.x + f.x + g.x); o.y = f2bf(r.y + f.y + g.y);
  o.z = f2bf(r.z + f.z + g.z); o.w = f2bf(r.w + f.w + g.w);
  ((ushort4*)xbf)[idx] = o;
}

// ---------------- bf16 MFMA GEMM: C = A @ W^T
// SPLITK>1: z = dir*SPLITK+kc, fp32 partials at C + z*M*N.
// EPI: 0 plain | 2 final scatter+bias | 4 in_proj split: n<1024 -> fp32 C, n>=1024 -> bf16 silu -> G
template<int BM,int BN,int SPLITK,int EPI>
__global__ __launch_bounds__(256) void mfma_nt(
    const u16* __restrict__ A, int lda, long sA,
    const u16* __restrict__ W, int ldw, long sW,
    const float* __restrict__ bias, u16* __restrict__ G,
    float* __restrict__ C, int ldc, long sC,
    int M, int N, int K)
{
  constexpr int WM = BM/2, WN = BN/2;
  constexpr int MI = WM/16, NI = WN/16;
  int z = blockIdx.z;
  int dir = z / SPLITK, kc = z % SPLITK;
  int Klen = K / SPLITK;
  int kbase = kc * Klen;
  A += (long)dir * sA;
  W += (long)dir * sW;
  if (SPLITK > 1) C += (long)z * M * N; else C += (long)dir * sC;
  if (EPI==4) G += (long)dir * (long)MT*DI;

  __shared__ u16 Al[BM*32];
  __shared__ u16 Wl[BN*32];
  int tid = threadIdx.x;
  int lane = tid & 63;
  int wave = tid >> 6;
  int wm0 = (wave>>1)*WM, wn0 = (wave&1)*WN;
  int m0 = blockIdx.y*BM, n0 = blockIdx.x*BN;
  int l16 = lane>>4, l15 = lane&15;

  f32x4 acc[MI][NI] = {};

  for (int k0=0; k0<Klen; k0+=32){
    #pragma unroll
    for (int it=0; it<BM*4/256; ++it){
      int ch = it*256 + tid;
      int row = ch % BM, kk = ch / BM;
      const u16* g = A + (long)(m0+row)*lda + kbase + k0 + kk*8;
      __builtin_amdgcn_global_load_lds(
          (const __attribute__((address_space(1))) void*)g,
          (__attribute__((address_space(3))) void*)(Al + ch*8), 16, 0, 0);
    }
    #pragma unroll
    for (int it=0; it<BN*4/256; ++it){
      int ch = it*256 + tid;
      int row = ch % BN, kk = ch / BN;
      const u16* g = W + (long)(n0+row)*ldw + kbase + k0 + kk*8;
      __builtin_amdgcn_global_load_lds(
          (const __attribute__((address_space(1))) void*)g,
          (__attribute__((address_space(3))) void*)(Wl + ch*8), 16, 0, 0);
    }
    __syncthreads();
    short8 a[MI], b[NI];
    #pragma unroll
    for (int i=0;i<MI;i++)
      a[i] = *(const short8*)&Al[(l16*BM + wm0 + i*16 + l15)*8];
    #pragma unroll
    for (int j=0;j<NI;j++)
      b[j] = *(const short8*)&Wl[(l16*BN + wn0 + j*16 + l15)*8];
    #pragma unroll
    for (int i=0;i<MI;i++)
      #pragma unroll
      for (int j=0;j<NI;j++)
        acc[i][j] = __builtin_amdgcn_mfma_f32_16x16x32_bf16(a[i], b[j], acc[i][j], 0,0,0);
    __syncthreads();
  }
  #pragma unroll
  for (int i=0;i<MI;i++){
    #pragma unroll
    for (int j=0;j<NI;j++){
      #pragma unroll
      for (int r=0;r<4;r++){
        int m = m0 + wm0 + i*16 + l16*4 + r;
        int n = n0 + wn0 + j*16 + l15;
        float v = acc[i][j][r];
        if (EPI==2){
          v += bias[n];
          int bb = m>>8, np_ = m&255, p = n>>8, dp = n&255;
          C[((long)(bb*1024 + np_*4 + p))*256 + dp] = v;
        } else if (EPI==4){
          if (n < 1024) C[(long)m*1024 + n] = v;
          else          G[(long)m*1024 + (n-1024)] = f2bf(v * sigmoidf_(v));
        } else {
          C[(long)m*ldc + n] = v;
        }
      }
    }
  }
}

// ---------------- split-K reduce for xproj
__global__ __launch_bounds__(256) void xreduce_k(const float* __restrict__ part,
    float* __restrict__ xdbl){
  int idx = blockIdx.x*256 + threadIdx.x;   // 131072
  int d = idx >> 16, off = idx & 65535;
  float s = 0.f;
  #pragma unroll
  for (int kc=0; kc<8; ++kc) s += part[((d*8+kc)<<16) + off];
  xdbl[idx] = s;
}

// ---------------- causal depthwise conv + bias + silu -> bf16 u (reads dense xz_u)
__global__ __launch_bounds__(256) void conv_silu_k(const float* __restrict__ xzu,
    const float* __restrict__ cw, const float* __restrict__ cb,
    u16* __restrict__ ubf){
  int idx = blockIdx.x*256 + threadIdx.x;   // 2*MT*DI/4 = 524288
  int e = idx & (DI-1);
  int grp = idx >> 10;          // 512 groups: dir(1) | b(2) | lg(6)
  int dir = grp >> 8;
  int b   = (grp >> 6) & 3;
  int l0  = (grp & 63) * 4;
  long dm0 = (long)dir*MT + b*LL + l0;
  const float* w = cw + ((long)dir*DI + e)*4;
  float w0=w[0], w1=w[1], w2=w[2], w3=w[3];
  float bias = cb[dir*DI + e];
  const float* src = xzu + dm0*DI + e;     // row l0
  float vb[7];
  #pragma unroll
  for (int j=0;j<7;j++){
    int l = l0 - 3 + j;
    vb[j] = (l >= 0) ? src[(long)(j-3)*DI] : 0.f;
  }
  #pragma unroll
  for (int j=0;j<4;j++){
    float acc = bias;
    acc = fmaf(w0, vb[j],   acc);
    acc = fmaf(w1, vb[j+1], acc);
    acc = fmaf(w2, vb[j+2], acc);
    acc = fmaf(w3, vb[j+3], acc);
    float v = acc * sigmoidf_(acc);
    ubf[(dm0+j)*DI + e] = f2bf(v);
  }
}

// ---------------- selective scan with fused fp32 delta GEMM; padded LDS; pre-gated z
__global__ __launch_bounds__(256) void scan_k(
    const u16* __restrict__ ubf, const u16* __restrict__ gbf,
    const float* __restrict__ xdbl, const float* __restrict__ dtw,
    const float* __restrict__ dtb, const float* __restrict__ A_log,
    const float* __restrict__ Dp, u16* __restrict__ ygbf)
{
  int t = threadIdx.x;
  int n = t & 15, el = t >> 4;
  int ec = blockIdx.x, b = blockIdx.y, dir = blockIdx.z;
  int e0 = ec*16, e = e0 + el;
  float Av = -__expf(A_log[((long)dir*DI + e)*16 + n]);
  float Dv = Dp[dir*DI + e];
  long mbase = (long)dir*MT + b*LL;
  const u16* up_ = ubf + mbase*DI;
  const u16* gp_ = gbf + mbase*DI;
  const float* xd_ = xdbl + mbase*64;
  u16* yp_ = ygbf + mbase*DI;

  // dtw row (e0+n) in regs
  float wrow[32];
  {
    const float* wr = dtw + ((long)dir*DI + e0 + n)*32;
    #pragma unroll
    for (int r4=0;r4<8;r4++) *(float4*)&wrow[r4*4] = *(const float4*)&wr[r4*4];
  }
  float dtbv = dtb[dir*DI + e0 + n];

  __shared__ float sdt[2][CL][32];   // xdbl cols 0..31
  __shared__ float sBC[2][CL][32];   // B cols, C cols
  __shared__ float sU [2][CL][SP];
  __shared__ float sD [CL][SP];
  __shared__ float sy [CL][SP];

  float4 xv0, xv1; ushort4 uvv;
  auto load_pre = [&](int c){
    long l0 = (long)c*CL;
    int f0 = t, f1 = t + 256;   // 512 float4s = 32 rows x 16
    xv0 = *(const float4*)&xd_[(l0 + (f0>>4))*64 + (f0&15)*4];
    xv1 = *(const float4*)&xd_[(l0 + (f1>>4))*64 + (f1&15)*4];
    if (t < 128) uvv = *(const ushort4*)&up_[(l0 + (t>>2))*DI + e0 + (t&3)*4];
  };
  auto write_pre = [&](int buf){
    {
      int row = t>>4, c4 = (t&15)*4;
      if (c4 < 32) *(float4*)&sdt[buf][row][c4] = xv0;
      else         *(float4*)&sBC[buf][row][c4-32] = xv0;
    }
    {
      int f1 = t + 256;
      int row = f1>>4, c4 = (f1&15)*4;
      if (c4 < 32) *(float4*)&sdt[buf][row][c4] = xv1;
      else         *(float4*)&sBC[buf][row][c4-32] = xv1;
    }
    if (t < 128){
      float4 uf;
      uf.x = bf2f(uvv.x); uf.y = bf2f(uvv.y); uf.z = bf2f(uvv.z); uf.w = bf2f(uvv.w);
      *(float4*)&sU[buf][t>>2][(t&3)*4] = uf;
    }
  };

  load_pre(0);
  write_pre(0);
  load_pre(1);
  __syncthreads();

  float h = 0.f;
  for (int c = 0; c < NCH; ++c){
    int cur = c & 1;
    // delta for this chunk: thread computes 2 values at (l, e0+n)
    #pragma unroll
    for (int j=0;j<2;j++){
      int l = (t>>4)*2 + j;
      float acc = dtbv;
      #pragma unroll
      for (int r4=0;r4<8;r4++){
        float4 d4 = *(const float4*)&sdt[cur][l][r4*4];
        acc = fmaf(d4.x, wrow[r4*4],   acc);
        acc = fmaf(d4.y, wrow[r4*4+1], acc);
        acc = fmaf(d4.z, wrow[r4*4+2], acc);
        acc = fmaf(d4.w, wrow[r4*4+3], acc);
      }
      // fast stable softplus
      acc = fmaxf(acc, 0.f) + __logf(1.f + __expf(-fabsf(acc)));
      sD[l][n] = acc;
    }
    // issue gate load early (consumed in epilogue)
    ushort4 gv;
    if (t < 128) gv = *(const ushort4*)&gp_[((long)c*CL + (t>>2))*DI + e0 + (t&3)*4];
    __syncthreads();   // sD visible

    const float* pD  = &sD[0][el];
    const float* pU  = &sU[cur][0][el];
    const float* pBC = &sBC[cur][0][n];
    #pragma unroll
    for (int c8 = 0; c8 < 4; ++c8){
      const float* pD8  = pD  + c8*8*SP;
      const float* pU8  = pU  + c8*8*SP;
      const float* pBC8 = pBC + c8*256;
      #pragma unroll
      for (int l8 = 0; l8 < 8; ++l8){
        float dv = pD8[l8*SP];
        float uv = pU8[l8*SP];
        float Bv = pBC8[l8*32], Cv = pBC8[l8*32 + 16];
        float dA = __expf(dv*Av);
        h = fmaf(dA, h, dv*uv*Bv);
        float yc = sum16_dpp(h*Cv);
        if (n==0) sy[c8*8+l8][el] = yc + uv*Dv;
      }
    }
    __syncthreads();   // buffers cur & sD free; sy complete
    if (c+1 < NCH){
      write_pre(cur^1);
      if (c+2 < NCH) load_pre(c+2);
    }
    if (t < 128){
      float4 y4 = *(const float4*)&sy[t>>2][(t&3)*4];
      ushort4 o;
      o.x = f2bf(y4.x * bf2f(gv.x)); o.y = f2bf(y4.y * bf2f(gv.y));
      o.z = f2bf(y4.z * bf2f(gv.z)); o.w = f2bf(y4.w * bf2f(gv.w));
      *(ushort4*)&yp_[((long)c*CL + (t>>2))*DI + e0 + (t&3)*4] = o;
    }
    __syncthreads();
  }
}

extern "C" void kernel_launch(void* const* d_in, const int* in_sizes, int n_in,
                              void* d_out, int out_size, void* d_ws, size_t ws_size,
                              hipStream_t stream){
  const float* ts   = (const float*)d_in[0];
  const float* ew   = (const float*)d_in[2];
  const float* eb   = (const float*)d_in[3];
  const float* nw   = (const float*)d_in[4];
  const float* inw  = (const float*)d_in[5];
  const float* cw   = (const float*)d_in[6];
  const float* cb   = (const float*)d_in[7];
  const float* xpw  = (const float*)d_in[8];
  const float* dtw  = (const float*)d_in[9];
  const float* dtb  = (const float*)d_in[10];
  const float* alog = (const float*)d_in[11];
  const float* dpp  = (const float*)d_in[12];
  const float* outw = (const float*)d_in[13];
  const float* pw   = (const float*)d_in[14];
  const float* pb   = (const float*)d_in[15];
  float* out = (float*)d_out;

  float* ws   = (float*)d_ws;
  float* x    = ws;                  // 524288
  float* xzu  = ws + 524288;         // 2097152 (u pre-conv, both dirs)
  float* xdbl = ws + 2621440;        // 131072
  float* yout = ws + 2752512;        // 1048576
  float* xpart= ws + 3801088;        // 1048576 (2*8*65536)
  u16* ub     = (u16*)(ws + 4849664);
  u16* xn_bf  = ub;                  // 1048576 (both dirs)
  u16* u_bf   = ub + 1048576;        // 2097152
  u16* g_bf   = ub + 3145728;        // 2097152 (silu(z), both dirs)
  u16* yg_bf  = ub + 5242880;        // 2097152
  u16* x_bf   = ub + 7340032;        // 524288
  u16* wb     = ub + 7864320;        // 26738688 bf16 weights (in|out|xp|pj)
  u16* wb_in  = wb;                  // 16777216
  u16* wb_out = wb + 16777216;       // 8388608
  u16* wb_xp  = wb + 25165824;       // 1048576
  u16* wb_pj  = wb + 26214400;       // 524288

  dim3 blk(256);

  embed_k<<<MT*DM/256, blk, 0, stream>>>(ts, ew, eb, x);
  wcastall_k<<<26112, blk, 0, stream>>>(inw, outw, xpw, pw, wb);

  for (int i=0;i<NLAYER;i++){
    rmscomb_k<<<MT, blk, 0, stream>>>(x, i ? yout : nullptr, nw + i*DM,
        xn_bf, xn_bf + MT*DM);
    // in_proj: (1024x512)@(2048x512)^T; u-half -> xzu fp32, z-half -> silu bf16 g
    mfma_nt<64,128,1,4><<<dim3(16,16,2), blk, 0, stream>>>(
        xn_bf, DM, (long)MT*DM, wb_in + (long)i*2097152, DM, 1048576,
        nullptr, g_bf, xzu, 1024, (long)MT*1024, MT, 2048, DM);
    conv_silu_k<<<2048, blk, 0, stream>>>(xzu, cw + (long)i*2*DI*4, cb + i*2*DI, u_bf);
    // xproj: (1024x1024)@(64x1024)^T split-K=8, 64x64 tiles, 256 blocks
    mfma_nt<64,64,8,0><<<dim3(1,16,16), blk, 0, stream>>>(
        u_bf, DI, (long)MT*DI, wb_xp + (long)i*131072, DI, 65536,
        nullptr, nullptr, xpart, 64, 0, MT, 64, DI);
    xreduce_k<<<512, blk, 0, stream>>>(xpart, xdbl);
    // scan with fused fp32 delta-GEMM, pre-gated z
    scan_k<<<dim3(64, BS, 2), blk, 0, stream>>>(u_bf, g_bf, xdbl,
        dtw + (long)i*2*DI*DTR, dtb + (long)i*2*DI,
        alog + (long)i*2*DI*16, dpp + i*2*DI, yg_bf);
    // out_proj: (1024x1024)@(512x1024)^T; 64x64 tiles, 256 blocks
    mfma_nt<64,64,1,0><<<dim3(8,16,2), blk, 0, stream>>>(
        yg_bf, DI, (long)MT*DI, wb_out + (long)i*1048576, DI, 524288,
        nullptr, nullptr, yout, DM, (long)MT*DM, MT, DM, DI);
  }
  combcast_k<<<MT*DM/4/256, blk, 0, stream>>>(x, yout, x_bf);
  // final proj + bias + scatter; 64x64 tiles, 256 blocks
  mfma_nt<64,64,1,2><<<dim3(16,16,1), blk, 0, stream>>>(
      x_bf, DM, 0, wb_pj, DM, 0, pb, nullptr, out, 1024, 0, MT, 1024, DM);
}

// Round 11
// 750.205 us; speedup vs baseline: 1.5187x; 1.0216x over previous
//
#include <hip/hip_runtime.h>
#include <hip/hip_bf16.h>

#define DM 512      // d_model
#define DI 1024     // d_inner
#define DSTATE 16
#define DTR 32      // dt_rank
#define NLAYER 8
#define BS 4
#define LL 256      // tokens per batch (F*NP)
#define MT 1024     // BS*LL total tokens
#define DPROJ 256
#define CL 32       // scan chunk length
#define NCH (LL/CL)

typedef unsigned short u16;
typedef __attribute__((ext_vector_type(8))) short short8;
typedef __attribute__((ext_vector_type(4))) float f32x4;

__device__ __forceinline__ float sigmoidf_(float x){ return 1.f/(1.f+__expf(-x)); }

// fp32 -> bf16 round-to-nearest-even (finite inputs)
__device__ __forceinline__ u16 f2bf(float f){
  unsigned u = __float_as_uint(f);
  u = (u + 0x7FFF + ((u>>16)&1)) >> 16;
  return (u16)u;
}
__device__ __forceinline__ float bf2f(u16 v){
  return __uint_as_float(((unsigned)v) << 16);
}

// VALU-pipe 16-lane sum via DPP row rotations
template<int CTRL>
__device__ __forceinline__ float dpp_ror_add(float x){
  int y = __builtin_amdgcn_update_dpp(0, __float_as_int(x), CTRL, 0xF, 0xF, false);
  return x + __int_as_float(y);
}
__device__ __forceinline__ float sum16_dpp(float x){
  x = dpp_ror_add<0x128>(x);
  x = dpp_ror_add<0x124>(x);
  x = dpp_ror_add<0x122>(x);
  x = dpp_ror_add<0x121>(x);
  return x;
}

// ---------------- patch embed
__global__ __launch_bounds__(256) void embed_k(const float* __restrict__ ts,
    const float* __restrict__ ew, const float* __restrict__ eb, float* __restrict__ x){
  int idx = blockIdx.x*256 + threadIdx.x;     // MT*DM
  int m = idx >> 9, d = idx & 511;
  int b = m >> 8, np_ = m & 255;
  const float* t0 = ts + b*1024 + np_*4;
  float acc = eb[d];
  #pragma unroll
  for (int p=0;p<4;p++) acc = fmaf(t0[p], ew[d*4+p], acc);
  x[idx] = acc;
}

// ---------------- cast ALL weights to bf16 once; coalesced float4->ushort4
__global__ __launch_bounds__(256) void wcastall_k(
    const float* __restrict__ w_in, const float* __restrict__ w_out,
    const float* __restrict__ w_xp, const float* __restrict__ w_pj,
    u16* __restrict__ dst){
  int t = blockIdx.x*256 + threadIdx.x;   // 6684672 float4s
  long e4 = (long)t*4;
  const float* src; long o;
  if      (e4 < 16777216) { src = w_in;  o = e4; }
  else if (e4 < 25165824) { src = w_out; o = e4 - 16777216; }
  else if (e4 < 26214400) { src = w_xp;  o = e4 - 25165824; }
  else                    { src = w_pj;  o = e4 - 26214400; }
  float4 v = *(const float4*)(src + o);
  ushort4 r; r.x=f2bf(v.x); r.y=f2bf(v.y); r.z=f2bf(v.z); r.w=f2bf(v.w);
  *(ushort4*)(dst + e4) = r;
}

// ---------------- fused (residual combine) + rmsnorm -> bf16 normal+flipped
__global__ __launch_bounds__(256) void rmscomb_k(float* __restrict__ x,
    const float* __restrict__ yout,   // nullptr for layer 0
    const float* __restrict__ nw, u16* __restrict__ xnbf, u16* __restrict__ xnfbf){
  int m = blockIdx.x, t = threadIdx.x;
  int b = m>>8, l = m&255, mf = (b<<8)+(255-l);
  float2 v = *(const float2*)&x[(long)m*DM + t*2];
  if (yout){
    float2 f = *(const float2*)&yout[(long)m*DM + t*2];
    float2 g = *(const float2*)&yout[(long)MT*DM + (long)mf*DM + t*2];
    v.x += f.x + g.x; v.y += f.y + g.y;
    *(float2*)&x[(long)m*DM + t*2] = v;
  }
  float ss = v.x*v.x + v.y*v.y;
  ss += __shfl_down(ss,32); ss += __shfl_down(ss,16); ss += __shfl_down(ss,8);
  ss += __shfl_down(ss,4);  ss += __shfl_down(ss,2);  ss += __shfl_down(ss,1);
  __shared__ float ps[4];
  if ((t&63)==0) ps[t>>6] = ss;
  __syncthreads();
  float tot = ps[0]+ps[1]+ps[2]+ps[3];
  float rs = rsqrtf(tot*(1.f/DM) + 1e-5f);
  ushort2 o; o.x = f2bf(v.x*rs*nw[t*2]); o.y = f2bf(v.y*rs*nw[t*2+1]);
  *(ushort2*)&xnbf [(long)m *DM + t*2] = o;
  *(ushort2*)&xnfbf[(long)mf*DM + t*2] = o;
}

// ---------------- final combine + cast to bf16
__global__ __launch_bounds__(256) void combcast_k(const float* __restrict__ x,
    const float* __restrict__ yout, u16* __restrict__ xbf){
  int idx = blockIdx.x*256 + threadIdx.x;   // MT*DM/4
  int m = idx >> 7, c4 = idx & 127;
  int b = m>>8, l = m&255, mf = (b<<8)+(255-l);
  float4 r = ((const float4*)x)[idx];
  float4 f = ((const float4*)yout)[idx];
  float4 g = ((const float4*)(yout + (long)MT*DM))[(long)mf*128 + c4];
  ushort4 o;
  o.x = f2bf(r.x + f.x + g.x); o.y = f2bf(r.y + f.y + g.y);
  o.z = f2bf(r.z + f.z + g.z); o.w = f2bf(r.w + f.w + g.w);
  ((ushort4*)xbf)[idx] = o;
}

// ---------------- bf16 MFMA GEMM: C = A @ W^T
// SPLITK>1: z = dir*SPLITK+kc, fp32 partials at C + z*M*N.
// EPI: 0 plain | 2 final scatter+bias | 4 in_proj split: n<1024 -> fp32 C, n>=1024 -> bf16 silu -> G
template<int BM,int BN,int SPLITK,int EPI>
__global__ __launch_bounds__(256) void mfma_nt(
    const u16* __restrict__ A, int lda, long sA,
    const u16* __restrict__ W, int ldw, long sW,
    const float* __restrict__ bias, u16* __restrict__ G,
    float* __restrict__ C, int ldc, long sC,
    int M, int N, int K)
{
  constexpr int WM = BM/2, WN = BN/2;
  constexpr int MI = WM/16, NI = WN/16;
  int z = blockIdx.z;
  int dir = z / SPLITK, kc = z % SPLITK;
  int Klen = K / SPLITK;
  int kbase = kc * Klen;
  A += (long)dir * sA;
  W += (long)dir * sW;
  if (SPLITK > 1) C += (long)z * M * N; else C += (long)dir * sC;
  if (EPI==4) G += (long)dir * (long)MT*DI;

  __shared__ u16 Al[BM*32];
  __shared__ u16 Wl[BN*32];
  int tid = threadIdx.x;
  int lane = tid & 63;
  int wave = tid >> 6;
  int wm0 = (wave>>1)*WM, wn0 = (wave&1)*WN;
  int m0 = blockIdx.y*BM, n0 = blockIdx.x*BN;
  int l16 = lane>>4, l15 = lane&15;

  f32x4 acc[MI][NI] = {};

  for (int k0=0; k0<Klen; k0+=32){
    #pragma unroll
    for (int it=0; it<BM*4/256; ++it){
      int ch = it*256 + tid;
      int row = ch % BM, kk = ch / BM;
      const u16* g = A + (long)(m0+row)*lda + kbase + k0 + kk*8;
      __builtin_amdgcn_global_load_lds(
          (const __attribute__((address_space(1))) void*)g,
          (__attribute__((address_space(3))) void*)(Al + ch*8), 16, 0, 0);
    }
    #pragma unroll
    for (int it=0; it<BN*4/256; ++it){
      int ch = it*256 + tid;
      int row = ch % BN, kk = ch / BN;
      const u16* g = W + (long)(n0+row)*ldw + kbase + k0 + kk*8;
      __builtin_amdgcn_global_load_lds(
          (const __attribute__((address_space(1))) void*)g,
          (__attribute__((address_space(3))) void*)(Wl + ch*8), 16, 0, 0);
    }
    __syncthreads();
    short8 a[MI], b[NI];
    #pragma unroll
    for (int i=0;i<MI;i++)
      a[i] = *(const short8*)&Al[(l16*BM + wm0 + i*16 + l15)*8];
    #pragma unroll
    for (int j=0;j<NI;j++)
      b[j] = *(const short8*)&Wl[(l16*BN + wn0 + j*16 + l15)*8];
    #pragma unroll
    for (int i=0;i<MI;i++)
      #pragma unroll
      for (int j=0;j<NI;j++)
        acc[i][j] = __builtin_amdgcn_mfma_f32_16x16x32_bf16(a[i], b[j], acc[i][j], 0,0,0);
    __syncthreads();
  }
  #pragma unroll
  for (int i=0;i<MI;i++){
    #pragma unroll
    for (int j=0;j<NI;j++){
      #pragma unroll
      for (int r=0;r<4;r++){
        int m = m0 + wm0 + i*16 + l16*4 + r;
        int n = n0 + wn0 + j*16 + l15;
        float v = acc[i][j][r];
        if (EPI==2){
          v += bias[n];
          int bb = m>>8, np_ = m&255, p = n>>8, dp = n&255;
          C[((long)(bb*1024 + np_*4 + p))*256 + dp] = v;
        } else if (EPI==4){
          if (n < 1024) C[(long)m*1024 + n] = v;
          else          G[(long)m*1024 + (n-1024)] = f2bf(v * sigmoidf_(v));
        } else {
          C[(long)m*ldc + n] = v;
        }
      }
    }
  }
}

// ---------------- split-K reduce for xproj
__global__ __launch_bounds__(256) void xreduce_k(const float* __restrict__ part,
    float* __restrict__ xdbl){
  int idx = blockIdx.x*256 + threadIdx.x;   // 131072
  int d = idx >> 16, off = idx & 65535;
  float s = 0.f;
  #pragma unroll
  for (int kc=0; kc<8; ++kc) s += part[((d*8+kc)<<16) + off];
  xdbl[idx] = s;
}

// ---------------- causal depthwise conv + bias + silu -> bf16 u (reads dense xz_u)
__global__ __launch_bounds__(256) void conv_silu_k(const float* __restrict__ xzu,
    const float* __restrict__ cw, const float* __restrict__ cb,
    u16* __restrict__ ubf){
  int idx = blockIdx.x*256 + threadIdx.x;   // 2*MT*DI/4 = 524288
  int e = idx & (DI-1);
  int grp = idx >> 10;          // 512 groups: dir(1) | b(2) | lg(6)
  int dir = grp >> 8;
  int b   = (grp >> 6) & 3;
  int l0  = (grp & 63) * 4;
  long dm0 = (long)dir*MT + b*LL + l0;
  const float* w = cw + ((long)dir*DI + e)*4;
  float w0=w[0], w1=w[1], w2=w[2], w3=w[3];
  float bias = cb[dir*DI + e];
  const float* src = xzu + dm0*DI + e;     // row l0
  float vb[7];
  #pragma unroll
  for (int j=0;j<7;j++){
    int l = l0 - 3 + j;
    vb[j] = (l >= 0) ? src[(long)(j-3)*DI] : 0.f;
  }
  #pragma unroll
  for (int j=0;j<4;j++){
    float acc = bias;
    acc = fmaf(w0, vb[j],   acc);
    acc = fmaf(w1, vb[j+1], acc);
    acc = fmaf(w2, vb[j+2], acc);
    acc = fmaf(w3, vb[j+3], acc);
    float v = acc * sigmoidf_(acc);
    ubf[(dm0+j)*DI + e] = f2bf(v);
  }
}

// ---------------- selective scan; transposed pair-interleaved LDS, XCD-aware remap
// block = 256 threads = (el 0..15)x(n 0..15); grid (64, B, 2) remapped
__global__ __launch_bounds__(256) void scan_k(
    const u16* __restrict__ ubf, const u16* __restrict__ gbf,
    const float* __restrict__ xdbl, const float* __restrict__ dtw,
    const float* __restrict__ dtb, const float* __restrict__ A_log,
    const float* __restrict__ Dp, u16* __restrict__ ygbf)
{
  int t = threadIdx.x;
  int n = t & 15, el = t >> 4;
  // XCD-aware remap: 4 ec-adjacent blocks (sharing 128B u/g cache lines) -> same XCD
  int id = blockIdx.x + 64*blockIdx.y + 256*blockIdx.z;   // 0..511
  int xcd = id & 7, slot = id >> 3;                        // slot 0..63
  int ec = xcd*8 + (slot & 7);
  int bd = slot >> 3;                                      // 0..7
  int b = bd & 3, dir = bd >> 2;

  int e0 = ec*16, e = e0 + el;
  float Av = -__expf(A_log[((long)dir*DI + e)*16 + n]);
  float Dv = Dp[dir*DI + e];
  long mbase = (long)dir*MT + b*LL;
  const u16* up_ = ubf + mbase*DI;
  const u16* gp_ = gbf + mbase*DI;
  const float* xd_ = xdbl + mbase*64;
  u16* yp_ = ygbf + mbase*DI;

  // dtw row (e0+n) in regs
  float wrow[32];
  {
    const float* wr = dtw + ((long)dir*DI + e0 + n)*32;
    #pragma unroll
    for (int r4=0;r4<8;r4++) *(float4*)&wrow[r4*4] = *(const float4*)&wr[r4*4];
  }
  float dtbv = dtb[dir*DI + e0 + n];

  __shared__ float sDU[2][16][68];   // [el][l*2 + {0:d,1:u}], stride 68 (16B-aligned, 2-way)
  __shared__ float sBC[2][16][68];   // [n][l*2 + {0:B,1:C}]
  __shared__ float sdt[2][32][36];   // xdbl cols 0..31, padded
  __shared__ float sy [32][20];

  float4 xv0, xv1; ushort4 uvv;
  auto load_pre = [&](int c){
    long l0 = (long)c*CL;
    int f0 = t, f1 = t + 256;   // 512 float4s = 32 rows x 16
    xv0 = *(const float4*)&xd_[(l0 + (f0>>4))*64 + (f0&15)*4];
    xv1 = *(const float4*)&xd_[(l0 + (f1>>4))*64 + (f1&15)*4];
    if (t < 128) uvv = *(const ushort4*)&up_[(l0 + (t>>2))*DI + e0 + (t&3)*4];
  };
  auto write_pre = [&](int buf){
    #pragma unroll
    for (int h_=0; h_<2; ++h_){
      float4 xv = h_ ? xv1 : xv0;
      int f = t + h_*256;
      int row = f>>4, c4 = (f&15)*4;
      if (c4 < 32){
        *(float4*)&sdt[buf][row][c4] = xv;
      } else if (c4 < 48){
        int nb = c4 - 32;
        sBC[buf][nb  ][row*2] = xv.x; sBC[buf][nb+1][row*2] = xv.y;
        sBC[buf][nb+2][row*2] = xv.z; sBC[buf][nb+3][row*2] = xv.w;
      } else {
        int nb = c4 - 48;
        sBC[buf][nb  ][row*2+1] = xv.x; sBC[buf][nb+1][row*2+1] = xv.y;
        sBC[buf][nb+2][row*2+1] = xv.z; sBC[buf][nb+3][row*2+1] = xv.w;
      }
    }
    if (t < 128){
      int l = t>>2, e4 = (t&3)*4;
      sDU[buf][e4  ][l*2+1] = bf2f(uvv.x);
      sDU[buf][e4+1][l*2+1] = bf2f(uvv.y);
      sDU[buf][e4+2][l*2+1] = bf2f(uvv.z);
      sDU[buf][e4+3][l*2+1] = bf2f(uvv.w);
    }
  };

  load_pre(0);
  write_pre(0);
  load_pre(1);
  __syncthreads();

  float h = 0.f;
  int lp = t >> 4;
  for (int c = 0; c < NCH; ++c){
    int cur = c & 1;
    // delta: thread computes at (l = lp + j*16, e = e0+n); writes d-slot of sDU
    #pragma unroll
    for (int j=0;j<2;j++){
      int l = lp + j*16;
      float acc = dtbv;
      #pragma unroll
      for (int r4=0;r4<8;r4++){
        float4 d4 = *(const float4*)&sdt[cur][l][r4*4];
        acc = fmaf(d4.x, wrow[r4*4],   acc);
        acc = fmaf(d4.y, wrow[r4*4+1], acc);
        acc = fmaf(d4.z, wrow[r4*4+2], acc);
        acc = fmaf(d4.w, wrow[r4*4+3], acc);
      }
      acc = fmaxf(acc, 0.f) + __logf(1.f + __expf(-fabsf(acc)));
      sDU[cur][n][l*2] = acc;
    }
    // issue gate load early (consumed in epilogue)
    ushort4 gv;
    if (t < 128) gv = *(const ushort4*)&gp_[((long)c*CL + (t>>2))*DI + e0 + (t&3)*4];
    __syncthreads();   // d-slots visible

    const float* pDU = &sDU[cur][el][0];
    const float* pBC = &sBC[cur][n][0];
    #pragma unroll
    for (int l2 = 0; l2 < 16; ++l2){
      float4 du = *(const float4*)&pDU[l2*4];
      float4 bc = *(const float4*)&pBC[l2*4];
      {
        float dA = __expf(du.x*Av);
        h = fmaf(dA, h, du.x*du.y*bc.x);
        float yc = sum16_dpp(h*bc.y);
        if (n==0) sy[2*l2][el] = yc + du.y*Dv;
      }
      {
        float dA = __expf(du.z*Av);
        h = fmaf(dA, h, du.z*du.w*bc.z);
        float yc = sum16_dpp(h*bc.w);
        if (n==0) sy[2*l2+1][el] = yc + du.w*Dv;
      }
    }
    __syncthreads();   // buffers cur free; sy complete
    if (c+1 < NCH){
      write_pre(cur^1);
      if (c+2 < NCH) load_pre(c+2);
    }
    if (t < 128){
      float4 y4 = *(const float4*)&sy[t>>2][(t&3)*4];
      ushort4 o;
      o.x = f2bf(y4.x * bf2f(gv.x)); o.y = f2bf(y4.y * bf2f(gv.y));
      o.z = f2bf(y4.z * bf2f(gv.z)); o.w = f2bf(y4.w * bf2f(gv.w));
      *(ushort4*)&yp_[((long)c*CL + (t>>2))*DI + e0 + (t&3)*4] = o;
    }
    __syncthreads();
  }
}

extern "C" void kernel_launch(void* const* d_in, const int* in_sizes, int n_in,
                              void* d_out, int out_size, void* d_ws, size_t ws_size,
                              hipStream_t stream){
  const float* ts   = (const float*)d_in[0];
  const float* ew   = (const float*)d_in[2];
  const float* eb   = (const float*)d_in[3];
  const float* nw   = (const float*)d_in[4];
  const float* inw  = (const float*)d_in[5];
  const float* cw   = (const float*)d_in[6];
  const float* cb   = (const float*)d_in[7];
  const float* xpw  = (const float*)d_in[8];
  const float* dtw  = (const float*)d_in[9];
  const float* dtb  = (const float*)d_in[10];
  const float* alog = (const float*)d_in[11];
  const float* dpp  = (const float*)d_in[12];
  const float* outw = (const float*)d_in[13];
  const float* pw   = (const float*)d_in[14];
  const float* pb   = (const float*)d_in[15];
  float* out = (float*)d_out;

  float* ws   = (float*)d_ws;
  float* x    = ws;                  // 524288
  float* xzu  = ws + 524288;         // 2097152 (u pre-conv, both dirs)
  float* xdbl = ws + 2621440;        // 131072
  float* yout = ws + 2752512;        // 1048576
  float* xpart= ws + 3801088;        // 1048576 (2*8*65536)
  u16* ub     = (u16*)(ws + 4849664);
  u16* xn_bf  = ub;                  // 1048576 (both dirs)
  u16* u_bf   = ub + 1048576;        // 2097152
  u16* g_bf   = ub + 3145728;        // 2097152 (silu(z), both dirs)
  u16* yg_bf  = ub + 5242880;        // 2097152
  u16* x_bf   = ub + 7340032;        // 524288
  u16* wb     = ub + 7864320;        // 26738688 bf16 weights (in|out|xp|pj)
  u16* wb_in  = wb;                  // 16777216
  u16* wb_out = wb + 16777216;       // 8388608
  u16* wb_xp  = wb + 25165824;       // 1048576
  u16* wb_pj  = wb + 26214400;       // 524288

  dim3 blk(256);

  embed_k<<<MT*DM/256, blk, 0, stream>>>(ts, ew, eb, x);
  wcastall_k<<<26112, blk, 0, stream>>>(inw, outw, xpw, pw, wb);

  for (int i=0;i<NLAYER;i++){
    rmscomb_k<<<MT, blk, 0, stream>>>(x, i ? yout : nullptr, nw + i*DM,
        xn_bf, xn_bf + MT*DM);
    // in_proj: (1024x512)@(2048x512)^T; u-half -> xzu fp32, z-half -> silu bf16 g
    mfma_nt<64,128,1,4><<<dim3(16,16,2), blk, 0, stream>>>(
        xn_bf, DM, (long)MT*DM, wb_in + (long)i*2097152, DM, 1048576,
        nullptr, g_bf, xzu, 1024, (long)MT*1024, MT, 2048, DM);
    conv_silu_k<<<2048, blk, 0, stream>>>(xzu, cw + (long)i*2*DI*4, cb + i*2*DI, u_bf);
    // xproj: (1024x1024)@(64x1024)^T split-K=8, 64x64 tiles, 256 blocks
    mfma_nt<64,64,8,0><<<dim3(1,16,16), blk, 0, stream>>>(
        u_bf, DI, (long)MT*DI, wb_xp + (long)i*131072, DI, 65536,
        nullptr, nullptr, xpart, 64, 0, MT, 64, DI);
    xreduce_k<<<512, blk, 0, stream>>>(xpart, xdbl);
    // scan with fused fp32 delta-GEMM, pre-gated z
    scan_k<<<dim3(64, BS, 2), blk, 0, stream>>>(u_bf, g_bf, xdbl,
        dtw + (long)i*2*DI*DTR, dtb + (long)i*2*DI,
        alog + (long)i*2*DI*16, dpp + i*2*DI, yg_bf);
    // out_proj: (1024x1024)@(512x1024)^T; 64x64 tiles, 256 blocks
    mfma_nt<64,64,1,0><<<dim3(8,16,2), blk, 0, stream>>>(
        yg_bf, DI, (long)MT*DI, wb_out + (long)i*1048576, DI, 524288,
        nullptr, nullptr, yout, DM, (long)MT*DM, MT, DM, DI);
  }
  combcast_k<<<MT*DM/4/256, blk, 0, stream>>>(x, yout, x_bf);
  // final proj + bias + scatter; 64x64 tiles, 256 blocks
  mfma_nt<64,64,1,2><<<dim3(16,16,1), blk, 0, stream>>>(
      x_bf, DM, 0, wb_pj, DM, 0, pb, nullptr, out, 1024, 0, MT, 1024, DM);
}